// Round 5
// baseline (407.757 us; speedup 1.0000x reference)
//
#include <hip/hip_runtime.h>

#define C_DIM 384
#define S_DIM 196
#define CS_   (C_DIM * S_DIM)      // 75264 elements per (b) channel-plane
#define BCS   (32 * CS_)           // 2408448 elements per t-slab (B*C*S)
#define NELEM (128 * CS_)          // 9633792 total per tensor

typedef _Float16 half8  __attribute__((ext_vector_type(8)));
typedef float    floatx4 __attribute__((ext_vector_type(4)));

// ---------------------------------------------------------------------------
// Split weights into fp16 hi/lo(x4096) planes; precompute BN inv/sh (768 rows).
// ---------------------------------------------------------------------------
__global__ __launch_bounds__(256)
void split_w(const float* __restrict__ qw, const float* __restrict__ kw,
             const float* __restrict__ pw,
             const float* qg, const float* qb, const float* qm, const float* qv,
             const float* kg, const float* kb, const float* km, const float* kv,
             _Float16* __restrict__ Wq0, _Float16* __restrict__ Wq1,
             _Float16* __restrict__ Wp0, _Float16* __restrict__ Wp1,
             float2* __restrict__ invsh)
{
    const int i = blockIdx.x * 256 + threadIdx.x;
    const int NQ = 768 * C_DIM;
    if (i < NQ) {
        const int o = i / C_DIM, c = i - o * C_DIM;
        const float v = (o < 384) ? qw[o * C_DIM + c] : kw[(o - 384) * C_DIM + c];
        const _Float16 h0 = (_Float16)v;
        Wq0[i] = h0;
        Wq1[i] = (_Float16)((v - (float)h0) * 4096.0f);
    } else if (i < NQ + C_DIM * C_DIM) {
        const int j = i - NQ;
        const float v = pw[j];
        const _Float16 h0 = (_Float16)v;
        Wp0[j] = h0;
        Wp1[j] = (_Float16)((v - (float)h0) * 4096.0f);
    }
    if (i < 768) {
        float g, b, m, vv;
        if (i < 384) { g = qg[i]; b = qb[i]; m = qm[i]; vv = qv[i]; }
        else         { g = kg[i-384]; b = kb[i-384]; m = km[i-384]; vv = kv[i-384]; }
        const float inv = g / sqrtf(vv + 1e-5f);
        invsh[i] = make_float2(inv, b - m * inv);
    }
}

// ---------------------------------------------------------------------------
// Split + transpose X: [t][b][c][s] fp32 -> X0/X1 [m'=(b*196+s)*4+t][c] fp16.
// (b,s,t)-major columns so the 4 t-steps of one (b,s) are adjacent.
// ---------------------------------------------------------------------------
__global__ __launch_bounds__(256)
void split_x(const float* __restrict__ X,
             _Float16* __restrict__ X0, _Float16* __restrict__ X1)
{
    __shared__ float tile[32][201];
    const int tb = blockIdx.x;          // t*32 + b
    const int tt = tb >> 5, b = tb & 31;
    const int c0 = blockIdx.y * 32;
    const int t  = threadIdx.x;
    for (int idx = t; idx < 32 * S_DIM; idx += 256) {
        const int cc = idx / S_DIM, s = idx - cc * S_DIM;
        tile[cc][s] = X[(size_t)tb * CS_ + (c0 + cc) * S_DIM + s];
    }
    __syncthreads();
    for (int idx = t; idx < 32 * S_DIM; idx += 256) {
        const int s = idx >> 5, cc = idx & 31;
        const float v = tile[cc][s];
        const _Float16 h0 = (_Float16)v;
        const size_t off = ((size_t)(b * S_DIM + s) * 4 + tt) * C_DIM + c0 + cc;
        X0[off] = h0;
        X1[off] = (_Float16)((v - (float)h0) * 4096.0f);
    }
}

// ---------------------------------------------------------------------------
// Fused-split qk GEMM + BN + in-register LIF -> spike bytes.
// acc += A0*B1 + A1*B0 + (4096*A0)*B0; x = acc*2^-12*inv + sh; LIF over the
// 4 adjacent-lane t-columns; write 4-bit spike byte per (b,c,s).
// Register-prefetch staging (global->VGPR->ds_write_b128), XOR-swizzled LDS.
// ---------------------------------------------------------------------------
__global__ __launch_bounds__(256, 3)
void qk_mfma(const _Float16* __restrict__ A0, const _Float16* __restrict__ A1,
             const _Float16* __restrict__ B0, const _Float16* __restrict__ B1,
             const float2* __restrict__ invsh,
             unsigned char* __restrict__ spkQ, unsigned char* __restrict__ spkK)
{
    __shared__ __align__(16) _Float16 As0[128 * 32];
    __shared__ __align__(16) _Float16 As1[128 * 32];
    __shared__ __align__(16) _Float16 Bs0[128 * 32];
    __shared__ __align__(16) _Float16 Bs1[128 * 32];

    const int t    = threadIdx.x;
    const int wave = t >> 6, lane = t & 63;
    const int m0 = blockIdx.x * 128;
    const int o0 = blockIdx.y * 128;

    // staging: wave covers rows [wave*32, wave*32+32), 2 issues of 16 rows;
    // lane -> row ldR, global chunk (lane&3), LDS physical chunk XOR-swizzled
    const int wR  = wave * 32;
    const int ldR = lane >> 2;
    const int gC8 = (lane & 3) << 3;
    const int pC8 = ((lane & 3) ^ ((lane >> 3) & 3)) << 3;

    const int lo = lane & 15, quad = lane >> 4;
    const int oq = (wave >> 1) * 64, mq = (wave & 1) * 64;
    const int rdC = (quad ^ ((lo >> 1) & 3)) << 3;   // un-swizzled read chunk

    floatx4 acc[4][4];
    #pragma unroll
    for (int i = 0; i < 4; ++i)
        #pragma unroll
        for (int j = 0; j < 4; ++j) acc[i][j] = (floatx4)0.0f;

    uint4 ra0[2], ra1[2], rb0[2], rb1[2];
    #pragma unroll
    for (int u = 0; u < 2; ++u) {   // prologue: load kt=0
        const size_t ga = (size_t)(o0 + wR + u * 16 + ldR) * C_DIM + gC8;
        const size_t gb = (size_t)(m0 + wR + u * 16 + ldR) * C_DIM + gC8;
        ra0[u] = *(const uint4*)(A0 + ga);
        ra1[u] = *(const uint4*)(A1 + ga);
        rb0[u] = *(const uint4*)(B0 + gb);
        rb1[u] = *(const uint4*)(B1 + gb);
    }

    for (int kt = 0; kt < 12; ++kt) {
        __syncthreads();            // previous tile fully consumed
        #pragma unroll
        for (int u = 0; u < 2; ++u) {
            const int la = (wR + u * 16 + ldR) * 32 + pC8;
            *(uint4*)&As0[la] = ra0[u];
            *(uint4*)&As1[la] = ra1[u];
            *(uint4*)&Bs0[la] = rb0[u];
            *(uint4*)&Bs1[la] = rb1[u];
        }
        __syncthreads();            // tile ready
        if (kt < 11) {              // prefetch next iter into regs (overlaps MFMAs)
            const int kb = (kt + 1) * 32;
            #pragma unroll
            for (int u = 0; u < 2; ++u) {
                const size_t ga = (size_t)(o0 + wR + u * 16 + ldR) * C_DIM + kb + gC8;
                const size_t gb = (size_t)(m0 + wR + u * 16 + ldR) * C_DIM + kb + gC8;
                ra0[u] = *(const uint4*)(A0 + ga);
                ra1[u] = *(const uint4*)(A1 + ga);
                rb0[u] = *(const uint4*)(B0 + gb);
                rb1[u] = *(const uint4*)(B1 + gb);
            }
        }

        half8 a0F[4], a1F[4], b0F[4], b1F[4];
        #pragma unroll
        for (int i = 0; i < 4; ++i) {
            const int ra = (oq + i * 16 + lo) * 32 + rdC;
            a0F[i] = *(const half8*)&As0[ra];
            a1F[i] = *(const half8*)&As1[ra];
        }
        #pragma unroll
        for (int j = 0; j < 4; ++j) {
            const int rb = (mq + j * 16 + lo) * 32 + rdC;
            b0F[j] = *(const half8*)&Bs0[rb];
            b1F[j] = *(const half8*)&Bs1[rb];
        }
        #pragma unroll
        for (int i = 0; i < 4; ++i) {
            const half8 aS = a0F[i] * (_Float16)4096.0f;   // exact pow2 scale
            #pragma unroll
            for (int j = 0; j < 4; ++j) {
                acc[i][j] = __builtin_amdgcn_mfma_f32_16x16x32_f16(
                    a0F[i], b1F[j], acc[i][j], 0, 0, 0);
                acc[i][j] = __builtin_amdgcn_mfma_f32_16x16x32_f16(
                    a1F[i], b0F[j], acc[i][j], 0, 0, 0);
                acc[i][j] = __builtin_amdgcn_mfma_f32_16x16x32_f16(
                    aS,     b0F[j], acc[i][j], 0, 0, 0);
            }
        }
    }

    // epilogue: C/D layout col=lane&15, row=quad*4+reg. BN then cross-lane LIF
    // (cols = (b,s,t) with t = col&3; lanes 4g..4g+3 share one (b,s)).
    #pragma unroll
    for (int i = 0; i < 4; ++i) {
        #pragma unroll
        for (int r = 0; r < 4; ++r) {
            const int o = o0 + oq + i * 16 + quad * 4 + r;
            const float2 is = invsh[o];
            const float inv = is.x * (1.0f / 4096.0f);
            const float sh  = is.y;
            unsigned char* base = (o < 384) ? spkQ : spkK;
            const int orow = (o < 384) ? o : o - 384;
            #pragma unroll
            for (int j = 0; j < 4; ++j) {
                const float xv = acc[i][j][r] * inv + sh;
                const int g = lane & ~3;
                const float x0 = __shfl(xv, g + 0);
                const float x1 = __shfl(xv, g + 1);
                const float x2 = __shfl(xv, g + 2);
                const float x3 = __shfl(xv, g + 3);
                if ((lane & 3) == 0) {
                    float xs[4] = {x0, x1, x2, x3};
                    float v = 0.0f; int bits = 0;
                    #pragma unroll
                    for (int tt = 0; tt < 4; ++tt) {
                        const float h = v + (xs[tt] - v) * 0.5f;
                        const int sp = (h >= 1.0f);
                        v = sp ? 0.0f : h;
                        bits |= sp << tt;
                    }
                    const int m  = m0 + mq + j * 16 + lo;
                    const int bs = m >> 2;
                    const int b  = bs / S_DIM;
                    const int s2 = bs - b * S_DIM;
                    base[b * CS_ + orow * S_DIM + s2] = (unsigned char)bits;
                }
            }
        }
    }
}

// ---------------------------------------------------------------------------
// attn LIF (exact dyadic) per (b, head, s): sum q-spike bits over 48 channels,
// LIF v_th=0.5, emit 4 attn bits into attnB.
// ---------------------------------------------------------------------------
__global__ __launch_bounds__(256)
void attn_compute(const unsigned char* __restrict__ spkQ,
                  unsigned char* __restrict__ attnB)
{
    const int b    = blockIdx.x >> 3;
    const int head = blockIdx.x & 7;
    const int s    = threadIdx.x;
    if (s >= S_DIM) return;

    const unsigned char* sp = spkQ + b * CS_ + head * 48 * S_DIM + s;
    int qs[4] = {0, 0, 0, 0};
    #pragma unroll 4
    for (int c = 0; c < 48; ++c) {
        const int v = sp[c * S_DIM];
        qs[0] += v & 1;
        qs[1] += (v >> 1) & 1;
        qs[2] += (v >> 2) & 1;
        qs[3] += (v >> 3) & 1;
    }

    float va = 0.0f;
    int bits = 0;
    #pragma unroll
    for (int t = 0; t < 4; ++t) {
        const float h = va + ((float)qs[t] - va) * 0.5f;   // exact dyadic
        const int a = (h >= 0.5f);
        va = a ? 0.0f : h;
        bits |= a << t;
    }
    attnB[(b * 8 + head) * S_DIM + s] = (unsigned char)bits;
}

// ---------------------------------------------------------------------------
// Build proj B operand (t-major): Yt[m=tb*196+s][c] fp16 = attn & k_spike.
// ---------------------------------------------------------------------------
__global__ __launch_bounds__(256)
void build_y(const unsigned char* __restrict__ spkK,
             const unsigned char* __restrict__ attnB,
             unsigned short* __restrict__ Yt)
{
    __shared__ unsigned char tile[128][200];
    const int tb = blockIdx.x;          // t*32 + b
    const int b  = tb & 31, tt = tb >> 5;
    const int c0 = blockIdx.y * 128;
    const int t  = threadIdx.x;
    for (int idx = t; idx < 128 * S_DIM; idx += 256) {
        const int cc = idx / S_DIM, s = idx - cc * S_DIM;
        const int c = c0 + cc;
        const int kbit = (spkK[b * CS_ + c * S_DIM + s] >> tt) & 1;
        const int abit = (attnB[(b * 8 + c / 48) * S_DIM + s] >> tt) & 1;
        tile[cc][s] = (unsigned char)(kbit & abit);
    }
    __syncthreads();
    for (int idx = t; idx < 128 * S_DIM; idx += 256) {
        const int s = idx >> 7, cc = idx & 127;
        Yt[(size_t)(tb * S_DIM + s) * C_DIM + c0 + cc] = tile[cc][s] ? 0x3C00 : 0;
    }
}

// ---------------------------------------------------------------------------
// Fused-split proj GEMM: acc += A1*Y + (4096*A0)*Y, out = acc*2^-12 raw to P.
// Register-prefetch staging, 3 tiles.
// ---------------------------------------------------------------------------
__global__ __launch_bounds__(256, 3)
void proj_mfma(const _Float16* __restrict__ A0, const _Float16* __restrict__ A1,
               const _Float16* __restrict__ B0, float* __restrict__ P)
{
    __shared__ __align__(16) _Float16 As0[128 * 32];
    __shared__ __align__(16) _Float16 As1[128 * 32];
    __shared__ __align__(16) _Float16 Bs0[128 * 32];

    const int t    = threadIdx.x;
    const int wave = t >> 6, lane = t & 63;
    const int m0 = blockIdx.x * 128;
    const int o0 = blockIdx.y * 128;

    const int wR  = wave * 32;
    const int ldR = lane >> 2;
    const int gC8 = (lane & 3) << 3;
    const int pC8 = ((lane & 3) ^ ((lane >> 3) & 3)) << 3;

    const int lo = lane & 15, quad = lane >> 4;
    const int oq = (wave >> 1) * 64, mq = (wave & 1) * 64;
    const int rdC = (quad ^ ((lo >> 1) & 3)) << 3;

    floatx4 acc[4][4];
    #pragma unroll
    for (int i = 0; i < 4; ++i)
        #pragma unroll
        for (int j = 0; j < 4; ++j) acc[i][j] = (floatx4)0.0f;

    uint4 ra0[2], ra1[2], rb0[2];
    #pragma unroll
    for (int u = 0; u < 2; ++u) {
        const size_t ga = (size_t)(o0 + wR + u * 16 + ldR) * C_DIM + gC8;
        const size_t gb = (size_t)(m0 + wR + u * 16 + ldR) * C_DIM + gC8;
        ra0[u] = *(const uint4*)(A0 + ga);
        ra1[u] = *(const uint4*)(A1 + ga);
        rb0[u] = *(const uint4*)(B0 + gb);
    }

    for (int kt = 0; kt < 12; ++kt) {
        __syncthreads();
        #pragma unroll
        for (int u = 0; u < 2; ++u) {
            const int la = (wR + u * 16 + ldR) * 32 + pC8;
            *(uint4*)&As0[la] = ra0[u];
            *(uint4*)&As1[la] = ra1[u];
            *(uint4*)&Bs0[la] = rb0[u];
        }
        __syncthreads();
        if (kt < 11) {
            const int kb = (kt + 1) * 32;
            #pragma unroll
            for (int u = 0; u < 2; ++u) {
                const size_t ga = (size_t)(o0 + wR + u * 16 + ldR) * C_DIM + kb + gC8;
                const size_t gb = (size_t)(m0 + wR + u * 16 + ldR) * C_DIM + kb + gC8;
                ra0[u] = *(const uint4*)(A0 + ga);
                ra1[u] = *(const uint4*)(A1 + ga);
                rb0[u] = *(const uint4*)(B0 + gb);
            }
        }

        half8 a0F[4], a1F[4], bF[4];
        #pragma unroll
        for (int i = 0; i < 4; ++i) {
            const int ra = (oq + i * 16 + lo) * 32 + rdC;
            a0F[i] = *(const half8*)&As0[ra];
            a1F[i] = *(const half8*)&As1[ra];
        }
        #pragma unroll
        for (int j = 0; j < 4; ++j)
            bF[j] = *(const half8*)&Bs0[(mq + j * 16 + lo) * 32 + rdC];

        #pragma unroll
        for (int i = 0; i < 4; ++i) {
            const half8 aS = a0F[i] * (_Float16)4096.0f;
            #pragma unroll
            for (int j = 0; j < 4; ++j) {
                acc[i][j] = __builtin_amdgcn_mfma_f32_16x16x32_f16(
                    a1F[i], bF[j], acc[i][j], 0, 0, 0);
                acc[i][j] = __builtin_amdgcn_mfma_f32_16x16x32_f16(
                    aS,     bF[j], acc[i][j], 0, 0, 0);
            }
        }
    }

    #pragma unroll
    for (int i = 0; i < 4; ++i) {
        #pragma unroll
        for (int r = 0; r < 4; ++r) {
            const int o = o0 + oq + i * 16 + quad * 4 + r;
            #pragma unroll
            for (int j = 0; j < 4; ++j) {
                const int m  = m0 + mq + j * 16 + lo;
                const int tb = m / S_DIM;
                const int s  = m - tb * S_DIM;
                P[(size_t)tb * CS_ + o * S_DIM + s] = acc[i][j][r] * (1.0f / 4096.0f);
            }
        }
    }
}

// ---------------------------------------------------------------------------
// Final: bias, BN, LIF over t -> spikes to d_out.
// ---------------------------------------------------------------------------
__global__ __launch_bounds__(256)
void bn_lif_out(const float* __restrict__ P, const float* __restrict__ bias,
                const float* __restrict__ gamma, const float* __restrict__ beta,
                const float* __restrict__ mean,  const float* __restrict__ var,
                float* __restrict__ out)
{
    const int i = blockIdx.x * 256 + threadIdx.x;   // over B*C*S
    if (i >= BCS) return;
    const int o = (i % CS_) / S_DIM;
    const float inv = gamma[o] / sqrtf(var[o] + 1e-5f);
    const float sh  = beta[o] - mean[o] * inv;
    const float bv  = bias[o];

    float v = 0.0f;
    #pragma unroll
    for (int t = 0; t < 4; ++t) {
        const float z = (P[t * BCS + i] + bv) * inv + sh;
        const float h = v + (z - v) * 0.5f;
        const int sp = (h >= 1.0f);
        v = sp ? 0.0f : h;
        out[t * BCS + i] = sp ? 1.0f : 0.0f;
    }
}

// ---------------------------------------------------------------------------
extern "C" void kernel_launch(void* const* d_in, const int* in_sizes, int n_in,
                              void* d_out, int out_size, void* d_ws, size_t ws_size,
                              hipStream_t stream)
{
    const float* x          = (const float*)d_in[0];
    const float* q_w        = (const float*)d_in[1];
    const float* q_gamma    = (const float*)d_in[2];
    const float* q_beta     = (const float*)d_in[3];
    const float* q_mean     = (const float*)d_in[4];
    const float* q_var      = (const float*)d_in[5];
    const float* k_w        = (const float*)d_in[6];
    const float* k_gamma    = (const float*)d_in[7];
    const float* k_beta     = (const float*)d_in[8];
    const float* k_mean     = (const float*)d_in[9];
    const float* k_var      = (const float*)d_in[10];
    const float* proj_w     = (const float*)d_in[11];
    const float* proj_b     = (const float*)d_in[12];
    const float* proj_gamma = (const float*)d_in[13];
    const float* proj_beta  = (const float*)d_in[14];
    const float* proj_mean  = (const float*)d_in[15];
    const float* proj_var   = (const float*)d_in[16];
    float* out = (float*)d_out;

    // workspace layout (~83 MB):
    float*    f0 = (float*)d_ws;            // proj raw output P
    _Float16* h0 = (_Float16*)(f0 + NELEM); // X0 (b,s,t)-major; later Yt
    _Float16* h1 = h0 + NELEM;              // X1
    _Float16* Wq0 = h1 + NELEM;             // 768x384
    _Float16* Wq1 = Wq0 + 768 * C_DIM;
    _Float16* Wp0 = Wq1 + 768 * C_DIM;      // 384x384
    _Float16* Wp1 = Wp0 + C_DIM * C_DIM;
    float2*   invsh = (float2*)(Wp1 + C_DIM * C_DIM);   // 768 entries
    unsigned char* spkQ  = (unsigned char*)(invsh + 768);  // BCS bytes
    unsigned char* spkK  = spkQ + BCS;                     // BCS bytes
    unsigned char* attnB = spkK + BCS;                     // 50176 bytes

    split_w<<<1728, 256, 0, stream>>>(q_w, k_w, proj_w,
                                      q_gamma, q_beta, q_mean, q_var,
                                      k_gamma, k_beta, k_mean, k_var,
                                      Wq0, Wq1, Wp0, Wp1, invsh);
    split_x<<<dim3(128, 12), 256, 0, stream>>>(x, h0, h1);

    qk_mfma<<<dim3(196, 6), 256, 0, stream>>>(Wq0, Wq1, h0, h1, invsh,
                                              spkQ, spkK);

    attn_compute<<<256, 256, 0, stream>>>(spkQ, attnB);
    build_y<<<dim3(128, 3), 256, 0, stream>>>(spkK, attnB, (unsigned short*)h0);

    proj_mfma<<<dim3(196, 3), 256, 0, stream>>>(Wp0, Wp1, h0, f0);

    bn_lif_out<<<(BCS + 255) / 256, 256, 0, stream>>>(f0, proj_b,
                                                      proj_gamma, proj_beta,
                                                      proj_mean, proj_var, out);
}

// Round 6
// 368.679 us; speedup vs baseline: 1.1060x; 1.1060x over previous
//
#include <hip/hip_runtime.h>

#define C_DIM 384
#define S_DIM 196
#define CS_   (C_DIM * S_DIM)      // 75264
#define BCS   (32 * CS_)           // 2408448 elements per t-slab (B*C*S)
#define NELEM (128 * CS_)          // 9633792 total per tensor
#define NBS   6272                 // 32 * 196 (b,s) pairs

typedef _Float16 half8  __attribute__((ext_vector_type(8)));
typedef float    floatx4 __attribute__((ext_vector_type(4)));

// ---------------------------------------------------------------------------
// Split weights into fp16 hi/lo(x4096) planes; precompute BN inv/sh (768 rows).
// ---------------------------------------------------------------------------
__global__ __launch_bounds__(256)
void split_w(const float* __restrict__ qw, const float* __restrict__ kw,
             const float* __restrict__ pw,
             const float* qg, const float* qb, const float* qm, const float* qv,
             const float* kg, const float* kb, const float* km, const float* kv,
             _Float16* __restrict__ Wq0, _Float16* __restrict__ Wq1,
             _Float16* __restrict__ Wp0, _Float16* __restrict__ Wp1,
             float2* __restrict__ invsh)
{
    const int i = blockIdx.x * 256 + threadIdx.x;
    const int NQ = 768 * C_DIM;
    if (i < NQ) {
        const int o = i / C_DIM, c = i - o * C_DIM;
        const float v = (o < 384) ? qw[o * C_DIM + c] : kw[(o - 384) * C_DIM + c];
        const _Float16 h0 = (_Float16)v;
        Wq0[i] = h0;
        Wq1[i] = (_Float16)((v - (float)h0) * 4096.0f);
    } else if (i < NQ + C_DIM * C_DIM) {
        const int j = i - NQ;
        const float v = pw[j];
        const _Float16 h0 = (_Float16)v;
        Wp0[j] = h0;
        Wp1[j] = (_Float16)((v - (float)h0) * 4096.0f);
    }
    if (i < 768) {
        float g, b, m, vv;
        if (i < 384) { g = qg[i]; b = qb[i]; m = qm[i]; vv = qv[i]; }
        else         { g = kg[i-384]; b = kb[i-384]; m = km[i-384]; vv = kv[i-384]; }
        const float inv = g / sqrtf(vv + 1e-5f);
        invsh[i] = make_float2(inv, b - m * inv);
    }
}

// ---------------------------------------------------------------------------
// Split + transpose X: [t][b][c][s] fp32 -> X0/X1 [m'=(b*196+s)*4+t][c] fp16.
// ---------------------------------------------------------------------------
__global__ __launch_bounds__(256)
void split_x(const float* __restrict__ X,
             _Float16* __restrict__ X0, _Float16* __restrict__ X1)
{
    __shared__ float tile[32][201];
    const int tb = blockIdx.x;          // t*32 + b
    const int tt = tb >> 5, b = tb & 31;
    const int c0 = blockIdx.y * 32;
    const int t  = threadIdx.x;
    for (int idx = t; idx < 32 * S_DIM; idx += 256) {
        const int cc = idx / S_DIM, s = idx - cc * S_DIM;
        tile[cc][s] = X[(size_t)tb * CS_ + (c0 + cc) * S_DIM + s];
    }
    __syncthreads();
    for (int idx = t; idx < 32 * S_DIM; idx += 256) {
        const int s = idx >> 5, cc = idx & 31;
        const float v = tile[cc][s];
        const _Float16 h0 = (_Float16)v;
        const size_t off = ((size_t)(b * S_DIM + s) * 4 + tt) * C_DIM + c0 + cc;
        X0[off] = h0;
        X1[off] = (_Float16)((v - (float)h0) * 4096.0f);
    }
}

// ---------------------------------------------------------------------------
// Fused-split qk GEMM + BN + in-register LIF -> spike bytes, layout [bs][c]
// (c contiguous, 384 B rows; each block owns whole cache lines).
// acc += A0*B1 + A1*B0 + (4096*A0)*B0; x = acc*2^-12*inv + sh.
// ---------------------------------------------------------------------------
__global__ __launch_bounds__(256, 3)
void qk_mfma(const _Float16* __restrict__ A0, const _Float16* __restrict__ A1,
             const _Float16* __restrict__ B0, const _Float16* __restrict__ B1,
             const float2* __restrict__ invsh,
             unsigned char* __restrict__ spkQ, unsigned char* __restrict__ spkK)
{
    __shared__ __align__(16) _Float16 As0[128 * 32];
    __shared__ __align__(16) _Float16 As1[128 * 32];
    __shared__ __align__(16) _Float16 Bs0[128 * 32];
    __shared__ __align__(16) _Float16 Bs1[128 * 32];

    const int t    = threadIdx.x;
    const int wave = t >> 6, lane = t & 63;
    const int m0 = blockIdx.x * 128;
    const int o0 = blockIdx.y * 128;

    const int wR  = wave * 32;
    const int ldR = lane >> 2;
    const int gC8 = (lane & 3) << 3;
    const int pC8 = ((lane & 3) ^ ((lane >> 3) & 3)) << 3;

    const int lo = lane & 15, quad = lane >> 4;
    const int oq = (wave >> 1) * 64, mq = (wave & 1) * 64;
    const int rdC = (quad ^ ((lo >> 1) & 3)) << 3;

    floatx4 acc[4][4];
    #pragma unroll
    for (int i = 0; i < 4; ++i)
        #pragma unroll
        for (int j = 0; j < 4; ++j) acc[i][j] = (floatx4)0.0f;

    uint4 ra0[2], ra1[2], rb0[2], rb1[2];
    #pragma unroll
    for (int u = 0; u < 2; ++u) {
        const size_t ga = (size_t)(o0 + wR + u * 16 + ldR) * C_DIM + gC8;
        const size_t gb = (size_t)(m0 + wR + u * 16 + ldR) * C_DIM + gC8;
        ra0[u] = *(const uint4*)(A0 + ga);
        ra1[u] = *(const uint4*)(A1 + ga);
        rb0[u] = *(const uint4*)(B0 + gb);
        rb1[u] = *(const uint4*)(B1 + gb);
    }

    for (int kt = 0; kt < 12; ++kt) {
        __syncthreads();
        #pragma unroll
        for (int u = 0; u < 2; ++u) {
            const int la = (wR + u * 16 + ldR) * 32 + pC8;
            *(uint4*)&As0[la] = ra0[u];
            *(uint4*)&As1[la] = ra1[u];
            *(uint4*)&Bs0[la] = rb0[u];
            *(uint4*)&Bs1[la] = rb1[u];
        }
        __syncthreads();
        if (kt < 11) {
            const int kb = (kt + 1) * 32;
            #pragma unroll
            for (int u = 0; u < 2; ++u) {
                const size_t ga = (size_t)(o0 + wR + u * 16 + ldR) * C_DIM + kb + gC8;
                const size_t gb = (size_t)(m0 + wR + u * 16 + ldR) * C_DIM + kb + gC8;
                ra0[u] = *(const uint4*)(A0 + ga);
                ra1[u] = *(const uint4*)(A1 + ga);
                rb0[u] = *(const uint4*)(B0 + gb);
                rb1[u] = *(const uint4*)(B1 + gb);
            }
        }

        half8 a0F[4], a1F[4], b0F[4], b1F[4];
        #pragma unroll
        for (int i = 0; i < 4; ++i) {
            const int ra = (oq + i * 16 + lo) * 32 + rdC;
            a0F[i] = *(const half8*)&As0[ra];
            a1F[i] = *(const half8*)&As1[ra];
        }
        #pragma unroll
        for (int j = 0; j < 4; ++j) {
            const int rb = (mq + j * 16 + lo) * 32 + rdC;
            b0F[j] = *(const half8*)&Bs0[rb];
            b1F[j] = *(const half8*)&Bs1[rb];
        }
        #pragma unroll
        for (int i = 0; i < 4; ++i) {
            const half8 aS = a0F[i] * (_Float16)4096.0f;
            #pragma unroll
            for (int j = 0; j < 4; ++j) {
                acc[i][j] = __builtin_amdgcn_mfma_f32_16x16x32_f16(
                    a0F[i], b1F[j], acc[i][j], 0, 0, 0);
                acc[i][j] = __builtin_amdgcn_mfma_f32_16x16x32_f16(
                    a1F[i], b0F[j], acc[i][j], 0, 0, 0);
                acc[i][j] = __builtin_amdgcn_mfma_f32_16x16x32_f16(
                    aS,     b0F[j], acc[i][j], 0, 0, 0);
            }
        }
    }

    // epilogue: BN + cross-lane LIF; write spike byte to spk[bs*384 + c].
    #pragma unroll
    for (int i = 0; i < 4; ++i) {
        #pragma unroll
        for (int r = 0; r < 4; ++r) {
            const int o = o0 + oq + i * 16 + quad * 4 + r;
            const float2 is = invsh[o];
            const float inv = is.x * (1.0f / 4096.0f);
            const float sh  = is.y;
            unsigned char* base = (o < 384) ? spkQ : spkK;
            const int orow = (o < 384) ? o : o - 384;
            #pragma unroll
            for (int j = 0; j < 4; ++j) {
                const float xv = acc[i][j][r] * inv + sh;
                const int g = lane & ~3;
                const float x0 = __shfl(xv, g + 0);
                const float x1 = __shfl(xv, g + 1);
                const float x2 = __shfl(xv, g + 2);
                const float x3 = __shfl(xv, g + 3);
                if ((lane & 3) == 0) {
                    float xs[4] = {x0, x1, x2, x3};
                    float v = 0.0f; int bits = 0;
                    #pragma unroll
                    for (int tt = 0; tt < 4; ++tt) {
                        const float h = v + (xs[tt] - v) * 0.5f;
                        const int sp = (h >= 1.0f);
                        v = sp ? 0.0f : h;
                        bits |= sp << tt;
                    }
                    const int bs = (m0 + mq + j * 16 + lo) >> 2;
                    base[(size_t)bs * C_DIM + orow] = (unsigned char)bits;
                }
            }
        }
    }
}

// ---------------------------------------------------------------------------
// attn LIF per (bs, head): popcount q-spike bits over 48 contiguous bytes,
// exact-dyadic LIF v_th=0.5, emit 4 attn bits -> attnB[bs*8+head].
// ---------------------------------------------------------------------------
__global__ __launch_bounds__(256)
void attn_compute(const unsigned char* __restrict__ spkQ,
                  unsigned char* __restrict__ attnB)
{
    const int idx = blockIdx.x * 256 + threadIdx.x;   // bs*8 + head
    if (idx >= NBS * 8) return;
    const int bs = idx >> 3, head = idx & 7;
    const unsigned long long* p =
        (const unsigned long long*)(spkQ + (size_t)bs * C_DIM + head * 48);
    int qs[4] = {0, 0, 0, 0};
    #pragma unroll
    for (int u = 0; u < 6; ++u) {
        const unsigned long long v = p[u];
        qs[0] += __popcll(v & 0x0101010101010101ull);
        qs[1] += __popcll(v & 0x0202020202020202ull);
        qs[2] += __popcll(v & 0x0404040404040404ull);
        qs[3] += __popcll(v & 0x0808080808080808ull);
    }
    float va = 0.0f;
    int bits = 0;
    #pragma unroll
    for (int t = 0; t < 4; ++t) {
        const float h = va + ((float)qs[t] - va) * 0.5f;   // exact dyadic
        const int a = (h >= 0.5f);
        va = a ? 0.0f : h;
        bits |= a << t;
    }
    attnB[idx] = (unsigned char)bits;
}

// ---------------------------------------------------------------------------
// Fused-split proj GEMM; B operand built in-register from spike/attn bits
// (rows m' = bs*4+t, cols c); epilogue fuses bias+BN+LIF and writes d_out.
// acc += A1*Y + (4096*A0)*Y; sum = acc*2^-12.
// ---------------------------------------------------------------------------
__global__ __launch_bounds__(256, 3)
void proj_mfma(const _Float16* __restrict__ A0, const _Float16* __restrict__ A1,
               const unsigned char* __restrict__ spkK,
               const unsigned char* __restrict__ attnB,
               const float* __restrict__ bias, const float2* __restrict__ invsh,
               float* __restrict__ out)
{
    __shared__ __align__(16) _Float16 As0[128 * 32];
    __shared__ __align__(16) _Float16 As1[128 * 32];
    __shared__ __align__(16) _Float16 Bs0[128 * 32];

    const int t    = threadIdx.x;
    const int wave = t >> 6, lane = t & 63;
    const int m0 = blockIdx.x * 128;
    const int o0 = blockIdx.y * 128;

    const int wR  = wave * 32;
    const int ldR = lane >> 2;
    const int gC8 = (lane & 3) << 3;
    const int pC8 = ((lane & 3) ^ ((lane >> 3) & 3)) << 3;

    const int lo = lane & 15, quad = lane >> 4;
    const int oq = (wave >> 1) * 64, mq = (wave & 1) * 64;
    const int rdC = (quad ^ ((lo >> 1) & 3)) << 3;

    // B-build lane constants: row m' -> bs, tt
    const int bsL[2] = { (m0 + wR +  0 + ldR) >> 2, (m0 + wR + 16 + ldR) >> 2 };
    const int ttL    = (m0 + wR + ldR) & 3;

    floatx4 acc[4][4];
    #pragma unroll
    for (int i = 0; i < 4; ++i)
        #pragma unroll
        for (int j = 0; j < 4; ++j) acc[i][j] = (floatx4)0.0f;

    uint4 ra0[2], ra1[2];
    unsigned long long rk[2];
    int rab[2];
    {
        const int head0 = gC8 / 48;
        #pragma unroll
        for (int u = 0; u < 2; ++u) {
            const size_t ga = (size_t)(o0 + wR + u * 16 + ldR) * C_DIM + gC8;
            ra0[u] = *(const uint4*)(A0 + ga);
            ra1[u] = *(const uint4*)(A1 + ga);
            rk[u]  = *(const unsigned long long*)(spkK + (size_t)bsL[u] * C_DIM + gC8);
            rab[u] = (attnB[bsL[u] * 8 + head0] >> ttL) & 1;
        }
    }

    for (int kt = 0; kt < 12; ++kt) {
        __syncthreads();
        #pragma unroll
        for (int u = 0; u < 2; ++u) {
            const int la = (wR + u * 16 + ldR) * 32 + pC8;
            *(uint4*)&As0[la] = ra0[u];
            *(uint4*)&As1[la] = ra1[u];
            half8 bv;
            #pragma unroll
            for (int e = 0; e < 8; ++e)
                bv[e] = (_Float16)(float)((int)(rk[u] >> (8 * e + ttL)) & rab[u] & 1);
            *(half8*)&Bs0[la] = bv;
        }
        __syncthreads();
        if (kt < 11) {
            const int kb = (kt + 1) * 32;
            const int head = (kb + gC8) / 48;
            #pragma unroll
            for (int u = 0; u < 2; ++u) {
                const size_t ga = (size_t)(o0 + wR + u * 16 + ldR) * C_DIM + kb + gC8;
                ra0[u] = *(const uint4*)(A0 + ga);
                ra1[u] = *(const uint4*)(A1 + ga);
                rk[u]  = *(const unsigned long long*)(spkK + (size_t)bsL[u] * C_DIM + kb + gC8);
                rab[u] = (attnB[bsL[u] * 8 + head] >> ttL) & 1;
            }
        }

        half8 a0F[4], a1F[4], bF[4];
        #pragma unroll
        for (int i = 0; i < 4; ++i) {
            const int ra = (oq + i * 16 + lo) * 32 + rdC;
            a0F[i] = *(const half8*)&As0[ra];
            a1F[i] = *(const half8*)&As1[ra];
        }
        #pragma unroll
        for (int j = 0; j < 4; ++j)
            bF[j] = *(const half8*)&Bs0[(mq + j * 16 + lo) * 32 + rdC];

        #pragma unroll
        for (int i = 0; i < 4; ++i) {
            const half8 aS = a0F[i] * (_Float16)4096.0f;
            #pragma unroll
            for (int j = 0; j < 4; ++j) {
                acc[i][j] = __builtin_amdgcn_mfma_f32_16x16x32_f16(
                    a1F[i], bF[j], acc[i][j], 0, 0, 0);
                acc[i][j] = __builtin_amdgcn_mfma_f32_16x16x32_f16(
                    aS,     bF[j], acc[i][j], 0, 0, 0);
            }
        }
    }

    // epilogue: bias+BN, cross-lane LIF over t, write {0,1} fp32 to d_out.
    #pragma unroll
    for (int i = 0; i < 4; ++i) {
        #pragma unroll
        for (int r = 0; r < 4; ++r) {
            const int o  = o0 + oq + i * 16 + quad * 4 + r;
            const float2 is = invsh[o];
            const float bv = bias[o];
            #pragma unroll
            for (int j = 0; j < 4; ++j) {
                const float p  = acc[i][j][r] * (1.0f / 4096.0f);
                const float zv = (p + bv) * is.x + is.y;
                const int g = lane & ~3;
                const float z0 = __shfl(zv, g + 0);
                const float z1 = __shfl(zv, g + 1);
                const float z2 = __shfl(zv, g + 2);
                const float z3 = __shfl(zv, g + 3);
                if ((lane & 3) == 0) {
                    float zs[4] = {z0, z1, z2, z3};
                    const int bs = (m0 + mq + j * 16 + lo) >> 2;
                    const int b  = bs / S_DIM;
                    const int s  = bs - b * S_DIM;
                    float* op = out + (size_t)b * CS_ + o * S_DIM + s;
                    float v = 0.0f;
                    #pragma unroll
                    for (int tt = 0; tt < 4; ++tt) {
                        const float h = v + (zs[tt] - v) * 0.5f;
                        const int sp = (h >= 1.0f);
                        v = sp ? 0.0f : h;
                        op[(size_t)tt * BCS] = sp ? 1.0f : 0.0f;
                    }
                }
            }
        }
    }
}

// ---------------------------------------------------------------------------
extern "C" void kernel_launch(void* const* d_in, const int* in_sizes, int n_in,
                              void* d_out, int out_size, void* d_ws, size_t ws_size,
                              hipStream_t stream)
{
    const float* x          = (const float*)d_in[0];
    const float* q_w        = (const float*)d_in[1];
    const float* q_gamma    = (const float*)d_in[2];
    const float* q_beta     = (const float*)d_in[3];
    const float* q_mean     = (const float*)d_in[4];
    const float* q_var      = (const float*)d_in[5];
    const float* k_w        = (const float*)d_in[6];
    const float* k_gamma    = (const float*)d_in[7];
    const float* k_beta     = (const float*)d_in[8];
    const float* k_mean     = (const float*)d_in[9];
    const float* k_var      = (const float*)d_in[10];
    const float* proj_w     = (const float*)d_in[11];
    const float* proj_b     = (const float*)d_in[12];
    const float* proj_gamma = (const float*)d_in[13];
    const float* proj_beta  = (const float*)d_in[14];
    const float* proj_mean  = (const float*)d_in[15];
    const float* proj_var   = (const float*)d_in[16];
    float* out = (float*)d_out;

    // workspace (~45 MB):
    _Float16* h0 = (_Float16*)d_ws;         // X0 (b,s,t)-major
    _Float16* h1 = h0 + NELEM;              // X1
    _Float16* Wq0 = h1 + NELEM;             // 768x384
    _Float16* Wq1 = Wq0 + 768 * C_DIM;
    _Float16* Wp0 = Wq1 + 768 * C_DIM;      // 384x384
    _Float16* Wp1 = Wp0 + C_DIM * C_DIM;
    float2*   invshQ = (float2*)(Wp1 + C_DIM * C_DIM);   // 768 (q|k)
    float2*   invshP = invshQ + 768;                     // 384 (proj)
    unsigned char* spkQ  = (unsigned char*)(invshP + 384);  // NBS*384
    unsigned char* spkK  = spkQ + (size_t)NBS * C_DIM;
    unsigned char* attnB = spkK + (size_t)NBS * C_DIM;      // NBS*8

    split_w<<<1728, 256, 0, stream>>>(q_w, k_w, proj_w,
                                      q_gamma, q_beta, q_mean, q_var,
                                      k_gamma, k_beta, k_mean, k_var,
                                      Wq0, Wq1, Wp0, Wp1, invshQ);
    // proj BN constants (reuse split_w shape via small inline kernel):
    // pack into invshP with a tiny lambda-style kernel launch
    {
        struct L { static __global__ void k(const float* g, const float* b,
                                            const float* m, const float* v,
                                            float2* is) {
            const int i = blockIdx.x * 64 + threadIdx.x;
            if (i < 384) {
                const float inv = g[i] / sqrtf(v[i] + 1e-5f);
                is[i] = make_float2(inv, b[i] - m[i] * inv);
            }
        } };
        L::k<<<6, 64, 0, stream>>>(proj_gamma, proj_beta, proj_mean, proj_var,
                                   invshP);
    }
    split_x<<<dim3(128, 12), 256, 0, stream>>>(x, h0, h1);

    qk_mfma<<<dim3(196, 6), 256, 0, stream>>>(Wq0, Wq1, h0, h1, invshQ,
                                              spkQ, spkK);
    attn_compute<<<196, 256, 0, stream>>>(spkQ, attnB);
    proj_mfma<<<dim3(196, 3), 256, 0, stream>>>(Wp0, Wp1, spkK, attnB,
                                                proj_b, invshP, out);
}

// Round 7
// 232.248 us; speedup vs baseline: 1.7557x; 1.5874x over previous
//
#include <hip/hip_runtime.h>

#define C_DIM 384
#define S_DIM 196
#define CS_   (C_DIM * S_DIM)      // 75264
#define BCS   (32 * CS_)           // 2408448 elements per t-slab (B*C*S)
#define NELEM (128 * CS_)          // 9633792 total per tensor
#define NBS   6272                 // 32 * 196 (b,s) pairs

typedef _Float16 half8  __attribute__((ext_vector_type(8)));
typedef float    floatx4 __attribute__((ext_vector_type(4)));

// async 16B/lane global->LDS copy; LDS base wave-uniform, HW adds lane*16.
__device__ __forceinline__ void gl_lds16(const _Float16* g, _Float16* l) {
    __builtin_amdgcn_global_load_lds(
        (const __attribute__((address_space(1))) unsigned int*)g,
        (__attribute__((address_space(3))) unsigned int*)l, 16, 0, 0);
}

// ---------------------------------------------------------------------------
// Split weights into fp16 hi/lo(x4096) planes; precompute BN inv/sh (768 rows).
// ---------------------------------------------------------------------------
__global__ __launch_bounds__(256)
void split_w(const float* __restrict__ qw, const float* __restrict__ kw,
             const float* __restrict__ pw,
             const float* qg, const float* qb, const float* qm, const float* qv,
             const float* kg, const float* kb, const float* km, const float* kv,
             _Float16* __restrict__ Wq0, _Float16* __restrict__ Wq1,
             _Float16* __restrict__ Wp0, _Float16* __restrict__ Wp1,
             float2* __restrict__ invsh)
{
    const int i = blockIdx.x * 256 + threadIdx.x;
    const int NQ = 768 * C_DIM;
    if (i < NQ) {
        const int o = i / C_DIM, c = i - o * C_DIM;
        const float v = (o < 384) ? qw[o * C_DIM + c] : kw[(o - 384) * C_DIM + c];
        const _Float16 h0 = (_Float16)v;
        Wq0[i] = h0;
        Wq1[i] = (_Float16)((v - (float)h0) * 4096.0f);
    } else if (i < NQ + C_DIM * C_DIM) {
        const int j = i - NQ;
        const float v = pw[j];
        const _Float16 h0 = (_Float16)v;
        Wp0[j] = h0;
        Wp1[j] = (_Float16)((v - (float)h0) * 4096.0f);
    }
    if (i < 768) {
        float g, b, m, vv;
        if (i < 384) { g = qg[i]; b = qb[i]; m = qm[i]; vv = qv[i]; }
        else         { g = kg[i-384]; b = kb[i-384]; m = km[i-384]; vv = kv[i-384]; }
        const float inv = g / sqrtf(vv + 1e-5f);
        invsh[i] = make_float2(inv, b - m * inv);
    }
}

// ---------------------------------------------------------------------------
// Split + transpose X: [t][b][c][s] fp32 -> X0/X1 [m'=(b*196+s)*4+t][c] fp16.
// ---------------------------------------------------------------------------
__global__ __launch_bounds__(256)
void split_x(const float* __restrict__ X,
             _Float16* __restrict__ X0, _Float16* __restrict__ X1)
{
    __shared__ float tile[32][201];
    const int tb = blockIdx.x;          // t*32 + b
    const int tt = tb >> 5, b = tb & 31;
    const int c0 = blockIdx.y * 32;
    const int t  = threadIdx.x;
    for (int idx = t; idx < 32 * S_DIM; idx += 256) {
        const int cc = idx / S_DIM, s = idx - cc * S_DIM;
        tile[cc][s] = X[(size_t)tb * CS_ + (c0 + cc) * S_DIM + s];
    }
    __syncthreads();
    for (int idx = t; idx < 32 * S_DIM; idx += 256) {
        const int s = idx >> 5, cc = idx & 31;
        const float v = tile[cc][s];
        const _Float16 h0 = (_Float16)v;
        const size_t off = ((size_t)(b * S_DIM + s) * 4 + tt) * C_DIM + c0 + cc;
        X0[off] = h0;
        X1[off] = (_Float16)((v - (float)h0) * 4096.0f);
    }
}

// ---------------------------------------------------------------------------
// Fused-split qk GEMM + BN + in-register LIF -> spike bytes [bs][c].
// acc += A0*B1 + A1*B0 + (4096*A0)*B0; x = acc*2^-12*inv + sh.
// global_load_lds staging (source-side XOR swizzle; no staging VGPRs).
// Spike bytes staged in LDS, written out as coalesced 128 B row chunks.
// ---------------------------------------------------------------------------
__global__ __launch_bounds__(256, 3)
void qk_mfma(const _Float16* __restrict__ A0, const _Float16* __restrict__ A1,
             const _Float16* __restrict__ B0, const _Float16* __restrict__ B1,
             const float2* __restrict__ invsh,
             unsigned char* __restrict__ spkQ, unsigned char* __restrict__ spkK)
{
    __shared__ __align__(16) _Float16 As0[128 * 32];
    __shared__ __align__(16) _Float16 As1[128 * 32];
    __shared__ __align__(16) _Float16 Bs0[128 * 32];
    __shared__ __align__(16) _Float16 Bs1[128 * 32];

    const int t    = threadIdx.x;
    const int wave = t >> 6, lane = t & 63;
    const int m0 = blockIdx.x * 128;
    const int o0 = blockIdx.y * 128;

    const int wR   = wave * 32;
    const int sRow = lane >> 2;
    const int sCol = (((lane & 3) ^ ((sRow >> 1) & 3))) << 3;

    const int lo = lane & 15, quad = lane >> 4;
    const int oq = (wave >> 1) * 64, mq = (wave & 1) * 64;
    const int rdC = (quad ^ ((lo >> 1) & 3)) << 3;

    floatx4 acc[4][4];
    #pragma unroll
    for (int i = 0; i < 4; ++i)
        #pragma unroll
        for (int j = 0; j < 4; ++j) acc[i][j] = (floatx4)0.0f;

    for (int kt = 0; kt < 12; ++kt) {
        __syncthreads();
        const int kb = kt * 32;
        #pragma unroll
        for (int u = 0; u < 2; ++u) {
            const int R = wR + u * 16;
            const size_t ga = (size_t)(o0 + R + sRow) * C_DIM + kb + sCol;
            const size_t gb = (size_t)(m0 + R + sRow) * C_DIM + kb + sCol;
            gl_lds16(A0 + ga, &As0[R * 32]);
            gl_lds16(A1 + ga, &As1[R * 32]);
            gl_lds16(B0 + gb, &Bs0[R * 32]);
            gl_lds16(B1 + gb, &Bs1[R * 32]);
        }
        __syncthreads();

        half8 a0F[4], a1F[4], b0F[4], b1F[4];
        #pragma unroll
        for (int i = 0; i < 4; ++i) {
            const int ra = (oq + i * 16 + lo) * 32 + rdC;
            a0F[i] = *(const half8*)&As0[ra];
            a1F[i] = *(const half8*)&As1[ra];
        }
        #pragma unroll
        for (int j = 0; j < 4; ++j) {
            const int rb = (mq + j * 16 + lo) * 32 + rdC;
            b0F[j] = *(const half8*)&Bs0[rb];
            b1F[j] = *(const half8*)&Bs1[rb];
        }
        #pragma unroll
        for (int i = 0; i < 4; ++i) {
            const half8 aS = a0F[i] * (_Float16)4096.0f;
            #pragma unroll
            for (int j = 0; j < 4; ++j) {
                acc[i][j] = __builtin_amdgcn_mfma_f32_16x16x32_f16(
                    a0F[i], b1F[j], acc[i][j], 0, 0, 0);
                acc[i][j] = __builtin_amdgcn_mfma_f32_16x16x32_f16(
                    a1F[i], b0F[j], acc[i][j], 0, 0, 0);
                acc[i][j] = __builtin_amdgcn_mfma_f32_16x16x32_f16(
                    aS,     b0F[j], acc[i][j], 0, 0, 0);
            }
        }
    }

    // epilogue: BN + cross-lane LIF -> LDS spike buffer -> coalesced writeout
    __syncthreads();
    unsigned char* sb = (unsigned char*)As0;    // 4 KB needed, 8 KB available
    #pragma unroll
    for (int i = 0; i < 4; ++i) {
        #pragma unroll
        for (int r = 0; r < 4; ++r) {
            const int o = o0 + oq + i * 16 + quad * 4 + r;
            const float2 is = invsh[o];
            const float inv = is.x * (1.0f / 4096.0f);
            const float sh  = is.y;
            #pragma unroll
            for (int j = 0; j < 4; ++j) {
                const float xv = acc[i][j][r] * inv + sh;
                const int g = lane & ~3;
                const float x0 = __shfl(xv, g + 0);
                const float x1 = __shfl(xv, g + 1);
                const float x2 = __shfl(xv, g + 2);
                const float x3 = __shfl(xv, g + 3);
                if ((lane & 3) == 0) {
                    float xs[4] = {x0, x1, x2, x3};
                    float v = 0.0f; int bits = 0;
                    #pragma unroll
                    for (int tt = 0; tt < 4; ++tt) {
                        const float h = v + (xs[tt] - v) * 0.5f;
                        const int sp = (h >= 1.0f);
                        v = sp ? 0.0f : h;
                        bits |= sp << tt;
                    }
                    const int bsl = (mq + j * 16 + lo) >> 2;
                    const int ol  = oq + i * 16 + quad * 4 + r;
                    sb[bsl * 128 + ol] = (unsigned char)bits;
                }
            }
        }
    }
    __syncthreads();
    {
        unsigned char* base = (o0 < 384) ? spkQ : spkK;
        const int o0c = (o0 < 384) ? o0 : o0 - 384;
        const int row = t >> 3, ch = t & 7;
        const uint4 v = *(const uint4*)&sb[row * 128 + ch * 16];
        *(uint4*)(base + (size_t)((m0 >> 2) + row) * C_DIM + o0c + ch * 16) = v;
    }
}

// ---------------------------------------------------------------------------
// attn LIF per (bs, head): popcount q-spike bits over 48 contiguous bytes.
// ---------------------------------------------------------------------------
__global__ __launch_bounds__(256)
void attn_compute(const unsigned char* __restrict__ spkQ,
                  unsigned char* __restrict__ attnB)
{
    const int idx = blockIdx.x * 256 + threadIdx.x;
    if (idx >= NBS * 8) return;
    const int bs = idx >> 3, head = idx & 7;
    const unsigned long long* p =
        (const unsigned long long*)(spkQ + (size_t)bs * C_DIM + head * 48);
    int qs[4] = {0, 0, 0, 0};
    #pragma unroll
    for (int u = 0; u < 6; ++u) {
        const unsigned long long v = p[u];
        qs[0] += __popcll(v & 0x0101010101010101ull);
        qs[1] += __popcll(v & 0x0202020202020202ull);
        qs[2] += __popcll(v & 0x0404040404040404ull);
        qs[3] += __popcll(v & 0x0808080808080808ull);
    }
    float va = 0.0f;
    int bits = 0;
    #pragma unroll
    for (int t = 0; t < 4; ++t) {
        const float h = va + ((float)qs[t] - va) * 0.5f;
        const int a = (h >= 0.5f);
        va = a ? 0.0f : h;
        bits |= a << t;
    }
    attnB[idx] = (unsigned char)bits;
}

// ---------------------------------------------------------------------------
// Fused-split proj GEMM; A via global_load_lds, B built in-register from
// spike/attn bits; epilogue fuses bias+BN+LIF and writes d_out.
// ---------------------------------------------------------------------------
__global__ __launch_bounds__(256, 3)
void proj_mfma(const _Float16* __restrict__ A0, const _Float16* __restrict__ A1,
               const unsigned char* __restrict__ spkK,
               const unsigned char* __restrict__ attnB,
               const float* __restrict__ bias, const float2* __restrict__ invsh,
               float* __restrict__ out)
{
    __shared__ __align__(16) _Float16 As0[128 * 32];
    __shared__ __align__(16) _Float16 As1[128 * 32];
    __shared__ __align__(16) _Float16 Bs0[128 * 32];

    const int t    = threadIdx.x;
    const int wave = t >> 6, lane = t & 63;
    const int m0 = blockIdx.x * 128;
    const int o0 = blockIdx.y * 128;

    const int wR   = wave * 32;
    const int sRow = lane >> 2;
    const int sCol = (((lane & 3) ^ ((sRow >> 1) & 3))) << 3;   // A glds swizzle
    const int gC8  = (lane & 3) << 3;                            // B global chunk
    const int pC8  = sCol;                                       // B LDS swizzle

    const int lo = lane & 15, quad = lane >> 4;
    const int oq = (wave >> 1) * 64, mq = (wave & 1) * 64;
    const int rdC = (quad ^ ((lo >> 1) & 3)) << 3;

    const int bsL[2] = { (m0 + wR +  0 + sRow) >> 2, (m0 + wR + 16 + sRow) >> 2 };
    const int ttL    = (m0 + wR + sRow) & 3;

    floatx4 acc[4][4];
    #pragma unroll
    for (int i = 0; i < 4; ++i)
        #pragma unroll
        for (int j = 0; j < 4; ++j) acc[i][j] = (floatx4)0.0f;

    unsigned long long rk[2];
    int rab[2];
    {
        const int head0 = gC8 / 48;
        #pragma unroll
        for (int u = 0; u < 2; ++u) {
            rk[u]  = *(const unsigned long long*)(spkK + (size_t)bsL[u] * C_DIM + gC8);
            rab[u] = (attnB[bsL[u] * 8 + head0] >> ttL) & 1;
        }
    }

    for (int kt = 0; kt < 12; ++kt) {
        __syncthreads();
        const int kb = kt * 32;
        #pragma unroll
        for (int u = 0; u < 2; ++u) {
            const int R = wR + u * 16;
            half8 bv;
            #pragma unroll
            for (int e = 0; e < 8; ++e)
                bv[e] = (_Float16)(float)((int)(rk[u] >> (8 * e + ttL)) & rab[u] & 1);
            *(half8*)&Bs0[(R + sRow) * 32 + pC8] = bv;
            const size_t ga = (size_t)(o0 + R + sRow) * C_DIM + kb + sCol;
            gl_lds16(A0 + ga, &As0[R * 32]);
            gl_lds16(A1 + ga, &As1[R * 32]);
        }
        if (kt < 11) {
            const int kb2  = (kt + 1) * 32;
            const int head = (kb2 + gC8) / 48;
            #pragma unroll
            for (int u = 0; u < 2; ++u) {
                rk[u]  = *(const unsigned long long*)(spkK + (size_t)bsL[u] * C_DIM + kb2 + gC8);
                rab[u] = (attnB[bsL[u] * 8 + head] >> ttL) & 1;
            }
        }
        __syncthreads();

        half8 a0F[4], a1F[4], bF[4];
        #pragma unroll
        for (int i = 0; i < 4; ++i) {
            const int ra = (oq + i * 16 + lo) * 32 + rdC;
            a0F[i] = *(const half8*)&As0[ra];
            a1F[i] = *(const half8*)&As1[ra];
        }
        #pragma unroll
        for (int j = 0; j < 4; ++j)
            bF[j] = *(const half8*)&Bs0[(mq + j * 16 + lo) * 32 + rdC];

        #pragma unroll
        for (int i = 0; i < 4; ++i) {
            const half8 aS = a0F[i] * (_Float16)4096.0f;
            #pragma unroll
            for (int j = 0; j < 4; ++j) {
                acc[i][j] = __builtin_amdgcn_mfma_f32_16x16x32_f16(
                    a1F[i], bF[j], acc[i][j], 0, 0, 0);
                acc[i][j] = __builtin_amdgcn_mfma_f32_16x16x32_f16(
                    aS,     bF[j], acc[i][j], 0, 0, 0);
            }
        }
    }

    #pragma unroll
    for (int i = 0; i < 4; ++i) {
        #pragma unroll
        for (int r = 0; r < 4; ++r) {
            const int o  = o0 + oq + i * 16 + quad * 4 + r;
            const float2 is = invsh[o];
            const float bv = bias[o];
            #pragma unroll
            for (int j = 0; j < 4; ++j) {
                const float p  = acc[i][j][r] * (1.0f / 4096.0f);
                const float zv = (p + bv) * is.x + is.y;
                const int g = lane & ~3;
                const float z0 = __shfl(zv, g + 0);
                const float z1 = __shfl(zv, g + 1);
                const float z2 = __shfl(zv, g + 2);
                const float z3 = __shfl(zv, g + 3);
                if ((lane & 3) == 0) {
                    float zs[4] = {z0, z1, z2, z3};
                    const int bs = (m0 + mq + j * 16 + lo) >> 2;
                    const int b  = bs / S_DIM;
                    const int s  = bs - b * S_DIM;
                    float* op = out + (size_t)b * CS_ + o * S_DIM + s;
                    float v = 0.0f;
                    #pragma unroll
                    for (int tt = 0; tt < 4; ++tt) {
                        const float h = v + (zs[tt] - v) * 0.5f;
                        const int sp = (h >= 1.0f);
                        v = sp ? 0.0f : h;
                        op[(size_t)tt * BCS] = sp ? 1.0f : 0.0f;
                    }
                }
            }
        }
    }
}

// ---------------------------------------------------------------------------
extern "C" void kernel_launch(void* const* d_in, const int* in_sizes, int n_in,
                              void* d_out, int out_size, void* d_ws, size_t ws_size,
                              hipStream_t stream)
{
    const float* x          = (const float*)d_in[0];
    const float* q_w        = (const float*)d_in[1];
    const float* q_gamma    = (const float*)d_in[2];
    const float* q_beta     = (const float*)d_in[3];
    const float* q_mean     = (const float*)d_in[4];
    const float* q_var      = (const float*)d_in[5];
    const float* k_w        = (const float*)d_in[6];
    const float* k_gamma    = (const float*)d_in[7];
    const float* k_beta     = (const float*)d_in[8];
    const float* k_mean     = (const float*)d_in[9];
    const float* k_var      = (const float*)d_in[10];
    const float* proj_w     = (const float*)d_in[11];
    const float* proj_b     = (const float*)d_in[12];
    const float* proj_gamma = (const float*)d_in[13];
    const float* proj_beta  = (const float*)d_in[14];
    const float* proj_mean  = (const float*)d_in[15];
    const float* proj_var   = (const float*)d_in[16];
    float* out = (float*)d_out;

    _Float16* h0 = (_Float16*)d_ws;         // X0 (b,s,t)-major
    _Float16* h1 = h0 + NELEM;              // X1
    _Float16* Wq0 = h1 + NELEM;             // 768x384
    _Float16* Wq1 = Wq0 + 768 * C_DIM;
    _Float16* Wp0 = Wq1 + 768 * C_DIM;      // 384x384
    _Float16* Wp1 = Wp0 + C_DIM * C_DIM;
    float2*   invshQ = (float2*)(Wp1 + C_DIM * C_DIM);   // 768 (q|k)
    float2*   invshP = invshQ + 768;                     // 384 (proj)
    unsigned char* spkQ  = (unsigned char*)(invshP + 384);  // NBS*384
    unsigned char* spkK  = spkQ + (size_t)NBS * C_DIM;
    unsigned char* attnB = spkK + (size_t)NBS * C_DIM;      // NBS*8

    split_w<<<1728, 256, 0, stream>>>(q_w, k_w, proj_w,
                                      q_gamma, q_beta, q_mean, q_var,
                                      k_gamma, k_beta, k_mean, k_var,
                                      Wq0, Wq1, Wp0, Wp1, invshQ);
    {
        struct L { static __global__ void k(const float* g, const float* b,
                                            const float* m, const float* v,
                                            float2* is) {
            const int i = blockIdx.x * 64 + threadIdx.x;
            if (i < 384) {
                const float inv = g[i] / sqrtf(v[i] + 1e-5f);
                is[i] = make_float2(inv, b[i] - m[i] * inv);
            }
        } };
        L::k<<<6, 64, 0, stream>>>(proj_gamma, proj_beta, proj_mean, proj_var,
                                   invshP);
    }
    split_x<<<dim3(128, 12), 256, 0, stream>>>(x, h0, h1);

    qk_mfma<<<dim3(196, 6), 256, 0, stream>>>(Wq0, Wq1, h0, h1, invshQ,
                                              spkQ, spkK);
    attn_compute<<<196, 256, 0, stream>>>(spkQ, attnB);
    proj_mfma<<<dim3(196, 3), 256, 0, stream>>>(Wp0, Wp1, spkK, attnB,
                                                proj_b, invshP, out);
}

// Round 8
// 218.628 us; speedup vs baseline: 1.8651x; 1.0623x over previous
//
#include <hip/hip_runtime.h>

#define C_DIM 384
#define S_DIM 196
#define CS_   (C_DIM * S_DIM)      // 75264
#define BCS   (32 * CS_)           // 2408448 elements per t-slab (B*C*S)
#define NELEM (128 * CS_)          // 9633792 total per tensor
#define NBS   6272                 // 32 * 196 (b,s) pairs

typedef _Float16 half8  __attribute__((ext_vector_type(8)));
typedef float    floatx4 __attribute__((ext_vector_type(4)));

// async 16B/lane global->LDS copy; LDS base wave-uniform, HW adds lane*16.
__device__ __forceinline__ void gl_lds16(const _Float16* g, _Float16* l) {
    __builtin_amdgcn_global_load_lds(
        (const __attribute__((address_space(1))) unsigned int*)g,
        (__attribute__((address_space(3))) unsigned int*)l, 16, 0, 0);
}

// ---------------------------------------------------------------------------
// Split weights into fp16 hi/lo(x4096) planes; precompute BN inv/sh (768 rows).
// ---------------------------------------------------------------------------
__global__ __launch_bounds__(256)
void split_w(const float* __restrict__ qw, const float* __restrict__ kw,
             const float* __restrict__ pw,
             const float* qg, const float* qb, const float* qm, const float* qv,
             const float* kg, const float* kb, const float* km, const float* kv,
             _Float16* __restrict__ Wq0, _Float16* __restrict__ Wq1,
             _Float16* __restrict__ Wp0, _Float16* __restrict__ Wp1,
             float2* __restrict__ invsh)
{
    const int i = blockIdx.x * 256 + threadIdx.x;
    const int NQ = 768 * C_DIM;
    if (i < NQ) {
        const int o = i / C_DIM, c = i - o * C_DIM;
        const float v = (o < 384) ? qw[o * C_DIM + c] : kw[(o - 384) * C_DIM + c];
        const _Float16 h0 = (_Float16)v;
        Wq0[i] = h0;
        Wq1[i] = (_Float16)((v - (float)h0) * 4096.0f);
    } else if (i < NQ + C_DIM * C_DIM) {
        const int j = i - NQ;
        const float v = pw[j];
        const _Float16 h0 = (_Float16)v;
        Wp0[j] = h0;
        Wp1[j] = (_Float16)((v - (float)h0) * 4096.0f);
    }
    if (i < 768) {
        float g, b, m, vv;
        if (i < 384) { g = qg[i]; b = qb[i]; m = qm[i]; vv = qv[i]; }
        else         { g = kg[i-384]; b = kb[i-384]; m = km[i-384]; vv = kv[i-384]; }
        const float inv = g / sqrtf(vv + 1e-5f);
        invsh[i] = make_float2(inv, b - m * inv);
    }
}

// ---------------------------------------------------------------------------
// Split + transpose X: [t][b][c][s] fp32 -> X0/X1 [m'=(b*196+s)*4+t][c] fp16.
// ---------------------------------------------------------------------------
__global__ __launch_bounds__(256)
void split_x(const float* __restrict__ X,
             _Float16* __restrict__ X0, _Float16* __restrict__ X1)
{
    __shared__ float tile[32][201];
    const int tb = blockIdx.x;          // t*32 + b
    const int tt = tb >> 5, b = tb & 31;
    const int c0 = blockIdx.y * 32;
    const int t  = threadIdx.x;
    for (int idx = t; idx < 32 * S_DIM; idx += 256) {
        const int cc = idx / S_DIM, s = idx - cc * S_DIM;
        tile[cc][s] = X[(size_t)tb * CS_ + (c0 + cc) * S_DIM + s];
    }
    __syncthreads();
    for (int idx = t; idx < 32 * S_DIM; idx += 256) {
        const int s = idx >> 5, cc = idx & 31;
        const float v = tile[cc][s];
        const _Float16 h0 = (_Float16)v;
        const size_t off = ((size_t)(b * S_DIM + s) * 4 + tt) * C_DIM + c0 + cc;
        X0[off] = h0;
        X1[off] = (_Float16)((v - (float)h0) * 4096.0f);
    }
}

// ---------------------------------------------------------------------------
// Fused-split qk GEMM + BN + IN-LANE LIF -> spike bytes [bs][c].
// X is the MFMA A-operand (D rows = m' = bs*4+t), W is the B-operand
// (D cols = o). acc += X0*W1 + X1*W0 + (4096*X0)*W0; x = acc*2^-12*inv+sh.
// Epilogue: LIF over the 4 regs of each fragment (t = reg), 1 byte/lane/frag.
// ---------------------------------------------------------------------------
__global__ __launch_bounds__(256, 3)
void qk_mfma(const _Float16* __restrict__ A0, const _Float16* __restrict__ A1,
             const _Float16* __restrict__ B0, const _Float16* __restrict__ B1,
             const float2* __restrict__ invsh,
             unsigned char* __restrict__ spkQ, unsigned char* __restrict__ spkK)
{
    __shared__ __align__(16) _Float16 As0[128 * 32];   // W0 tile (o rows)
    __shared__ __align__(16) _Float16 As1[128 * 32];   // W1 tile
    __shared__ __align__(16) _Float16 Bs0[128 * 32];   // X0 tile (m' rows)
    __shared__ __align__(16) _Float16 Bs1[128 * 32];   // X1 tile

    const int t    = threadIdx.x;
    const int wave = t >> 6, lane = t & 63;
    const int m0 = blockIdx.x * 128;
    const int o0 = blockIdx.y * 128;

    const int wR   = wave * 32;
    const int sRow = lane >> 2;
    const int sCol = (((lane & 3) ^ ((sRow >> 1) & 3))) << 3;

    const int lo = lane & 15, quad = lane >> 4;
    const int oq = (wave >> 1) * 64, mq = (wave & 1) * 64;
    const int rdC = (quad ^ ((lo >> 1) & 3)) << 3;

    floatx4 acc[4][4];   // [i = m-frag][j = o-frag]
    #pragma unroll
    for (int i = 0; i < 4; ++i)
        #pragma unroll
        for (int j = 0; j < 4; ++j) acc[i][j] = (floatx4)0.0f;

    for (int kt = 0; kt < 12; ++kt) {
        __syncthreads();
        const int kb = kt * 32;
        #pragma unroll
        for (int u = 0; u < 2; ++u) {
            const int R = wR + u * 16;
            const size_t ga = (size_t)(o0 + R + sRow) * C_DIM + kb + sCol;
            const size_t gb = (size_t)(m0 + R + sRow) * C_DIM + kb + sCol;
            gl_lds16(A0 + ga, &As0[R * 32]);
            gl_lds16(A1 + ga, &As1[R * 32]);
            gl_lds16(B0 + gb, &Bs0[R * 32]);
            gl_lds16(B1 + gb, &Bs1[R * 32]);
        }
        __syncthreads();

        half8 w0F[4], w1F[4], x0F[4], x1F[4];
        #pragma unroll
        for (int j = 0; j < 4; ++j) {
            const int ra = (oq + j * 16 + lo) * 32 + rdC;
            w0F[j] = *(const half8*)&As0[ra];
            w1F[j] = *(const half8*)&As1[ra];
        }
        #pragma unroll
        for (int i = 0; i < 4; ++i) {
            const int rb = (mq + i * 16 + lo) * 32 + rdC;
            x0F[i] = *(const half8*)&Bs0[rb];
            x1F[i] = *(const half8*)&Bs1[rb];
        }
        #pragma unroll
        for (int i = 0; i < 4; ++i) {
            const half8 xS = x0F[i] * (_Float16)4096.0f;   // exact pow2 scale
            #pragma unroll
            for (int j = 0; j < 4; ++j) {
                acc[i][j] = __builtin_amdgcn_mfma_f32_16x16x32_f16(
                    x0F[i], w1F[j], acc[i][j], 0, 0, 0);
                acc[i][j] = __builtin_amdgcn_mfma_f32_16x16x32_f16(
                    x1F[i], w0F[j], acc[i][j], 0, 0, 0);
                acc[i][j] = __builtin_amdgcn_mfma_f32_16x16x32_f16(
                    xS,     w0F[j], acc[i][j], 0, 0, 0);
            }
        }
    }

    // epilogue: D rows = m' (quad picks bs, reg picks t), cols = o.
    // In-lane LIF over the 4 regs; one spike byte per lane per fragment.
    #pragma unroll
    for (int j = 0; j < 4; ++j) {
        const int o = o0 + oq + j * 16 + lo;
        const float2 is = invsh[o];
        const float inv = is.x * (1.0f / 4096.0f);
        const float sh  = is.y;
        unsigned char* base = (o < 384) ? spkQ : spkK;
        const int orow = (o < 384) ? o : o - 384;
        #pragma unroll
        for (int i = 0; i < 4; ++i) {
            const int bs = ((m0 + mq + i * 16) >> 2) + quad;
            float v = 0.0f; int bits = 0;
            #pragma unroll
            for (int r = 0; r < 4; ++r) {
                const float xv = acc[i][j][r] * inv + sh;
                const float h = v + (xv - v) * 0.5f;
                const int sp = (h >= 1.0f);
                v = sp ? 0.0f : h;
                bits |= sp << r;
            }
            base[(size_t)bs * C_DIM + orow] = (unsigned char)bits;
        }
    }
}

// ---------------------------------------------------------------------------
// attn LIF per (bs, head): popcount q-spike bits over 48 contiguous bytes.
// ---------------------------------------------------------------------------
__global__ __launch_bounds__(256)
void attn_compute(const unsigned char* __restrict__ spkQ,
                  unsigned char* __restrict__ attnB)
{
    const int idx = blockIdx.x * 256 + threadIdx.x;
    if (idx >= NBS * 8) return;
    const int bs = idx >> 3, head = idx & 7;
    const unsigned long long* p =
        (const unsigned long long*)(spkQ + (size_t)bs * C_DIM + head * 48);
    int qs[4] = {0, 0, 0, 0};
    #pragma unroll
    for (int u = 0; u < 6; ++u) {
        const unsigned long long v = p[u];
        qs[0] += __popcll(v & 0x0101010101010101ull);
        qs[1] += __popcll(v & 0x0202020202020202ull);
        qs[2] += __popcll(v & 0x0404040404040404ull);
        qs[3] += __popcll(v & 0x0808080808080808ull);
    }
    float va = 0.0f;
    int bits = 0;
    #pragma unroll
    for (int t = 0; t < 4; ++t) {
        const float h = va + ((float)qs[t] - va) * 0.5f;
        const int a = (h >= 0.5f);
        va = a ? 0.0f : h;
        bits |= a << t;
    }
    attnB[idx] = (unsigned char)bits;
}

// ---------------------------------------------------------------------------
// Fused-split proj GEMM; Y (binary, from spike/attn bits) is the A-operand,
// W planes are the B-operand. acc += Y*W1 + Y*(4096*W0); sum = acc*2^-12.
// Epilogue: bias+BN per col o, in-lane LIF over regs (t), write d_out.
// ---------------------------------------------------------------------------
__global__ __launch_bounds__(256, 3)
void proj_mfma(const _Float16* __restrict__ A0, const _Float16* __restrict__ A1,
               const unsigned char* __restrict__ spkK,
               const unsigned char* __restrict__ attnB,
               const float* __restrict__ bias, const float2* __restrict__ invsh,
               float* __restrict__ out)
{
    __shared__ __align__(16) _Float16 As0[128 * 32];   // W0 (o rows)
    __shared__ __align__(16) _Float16 As1[128 * 32];   // W1
    __shared__ __align__(16) _Float16 Bs0[128 * 32];   // Y  (m' rows)

    const int t    = threadIdx.x;
    const int wave = t >> 6, lane = t & 63;
    const int m0 = blockIdx.x * 128;
    const int o0 = blockIdx.y * 128;

    const int wR   = wave * 32;
    const int sRow = lane >> 2;
    const int sCol = (((lane & 3) ^ ((sRow >> 1) & 3))) << 3;   // A glds swizzle
    const int gC8  = (lane & 3) << 3;                            // B global chunk
    const int pC8  = sCol;                                       // B LDS swizzle

    const int lo = lane & 15, quad = lane >> 4;
    const int oq = (wave >> 1) * 64, mq = (wave & 1) * 64;
    const int rdC = (quad ^ ((lo >> 1) & 3)) << 3;

    const int bsL[2] = { (m0 + wR +  0 + sRow) >> 2, (m0 + wR + 16 + sRow) >> 2 };
    const int ttL    = (m0 + wR + sRow) & 3;

    floatx4 acc[4][4];   // [i = m-frag][j = o-frag]
    #pragma unroll
    for (int i = 0; i < 4; ++i)
        #pragma unroll
        for (int j = 0; j < 4; ++j) acc[i][j] = (floatx4)0.0f;

    unsigned long long rk[2];
    int rab[2];
    {
        const int head0 = gC8 / 48;
        #pragma unroll
        for (int u = 0; u < 2; ++u) {
            rk[u]  = *(const unsigned long long*)(spkK + (size_t)bsL[u] * C_DIM + gC8);
            rab[u] = (attnB[bsL[u] * 8 + head0] >> ttL) & 1;
        }
    }

    for (int kt = 0; kt < 12; ++kt) {
        __syncthreads();
        const int kb = kt * 32;
        #pragma unroll
        for (int u = 0; u < 2; ++u) {
            const int R = wR + u * 16;
            half8 bv;
            #pragma unroll
            for (int e = 0; e < 8; ++e)
                bv[e] = (_Float16)(float)((int)(rk[u] >> (8 * e + ttL)) & rab[u] & 1);
            *(half8*)&Bs0[(R + sRow) * 32 + pC8] = bv;
            const size_t ga = (size_t)(o0 + R + sRow) * C_DIM + kb + sCol;
            gl_lds16(A0 + ga, &As0[R * 32]);
            gl_lds16(A1 + ga, &As1[R * 32]);
        }
        if (kt < 11) {
            const int kb2  = (kt + 1) * 32;
            const int head = (kb2 + gC8) / 48;
            #pragma unroll
            for (int u = 0; u < 2; ++u) {
                rk[u]  = *(const unsigned long long*)(spkK + (size_t)bsL[u] * C_DIM + kb2 + gC8);
                rab[u] = (attnB[bsL[u] * 8 + head] >> ttL) & 1;
            }
        }
        __syncthreads();

        half8 w0F[4], w1F[4], yF[4];
        #pragma unroll
        for (int j = 0; j < 4; ++j) {
            const int ra = (oq + j * 16 + lo) * 32 + rdC;
            w0F[j] = *(const half8*)&As0[ra];
            w1F[j] = *(const half8*)&As1[ra];
        }
        #pragma unroll
        for (int i = 0; i < 4; ++i)
            yF[i] = *(const half8*)&Bs0[(mq + i * 16 + lo) * 32 + rdC];

        #pragma unroll
        for (int j = 0; j < 4; ++j) {
            const half8 wS = w0F[j] * (_Float16)4096.0f;
            #pragma unroll
            for (int i = 0; i < 4; ++i) {
                acc[i][j] = __builtin_amdgcn_mfma_f32_16x16x32_f16(
                    yF[i], w1F[j], acc[i][j], 0, 0, 0);
                acc[i][j] = __builtin_amdgcn_mfma_f32_16x16x32_f16(
                    yF[i], wS,     acc[i][j], 0, 0, 0);
            }
        }
    }

    // epilogue: bias+BN per col o; in-lane LIF over regs (t = reg).
    #pragma unroll
    for (int j = 0; j < 4; ++j) {
        const int o = o0 + oq + j * 16 + lo;
        const float2 is = invsh[o];
        const float bv = bias[o];
        #pragma unroll
        for (int i = 0; i < 4; ++i) {
            const int bs = ((m0 + mq + i * 16) >> 2) + quad;
            const int b  = bs / S_DIM;
            const int s  = bs - b * S_DIM;
            float* op = out + (size_t)b * CS_ + o * S_DIM + s;
            float v = 0.0f;
            #pragma unroll
            for (int r = 0; r < 4; ++r) {
                const float p = acc[i][j][r] * (1.0f / 4096.0f);
                const float z = (p + bv) * is.x + is.y;
                const float h = v + (z - v) * 0.5f;
                const int sp = (h >= 1.0f);
                v = sp ? 0.0f : h;
                op[(size_t)r * BCS] = sp ? 1.0f : 0.0f;
            }
        }
    }
}

// ---------------------------------------------------------------------------
extern "C" void kernel_launch(void* const* d_in, const int* in_sizes, int n_in,
                              void* d_out, int out_size, void* d_ws, size_t ws_size,
                              hipStream_t stream)
{
    const float* x          = (const float*)d_in[0];
    const float* q_w        = (const float*)d_in[1];
    const float* q_gamma    = (const float*)d_in[2];
    const float* q_beta     = (const float*)d_in[3];
    const float* q_mean     = (const float*)d_in[4];
    const float* q_var      = (const float*)d_in[5];
    const float* k_w        = (const float*)d_in[6];
    const float* k_gamma    = (const float*)d_in[7];
    const float* k_beta     = (const float*)d_in[8];
    const float* k_mean     = (const float*)d_in[9];
    const float* k_var      = (const float*)d_in[10];
    const float* proj_w     = (const float*)d_in[11];
    const float* proj_b     = (const float*)d_in[12];
    const float* proj_gamma = (const float*)d_in[13];
    const float* proj_beta  = (const float*)d_in[14];
    const float* proj_mean  = (const float*)d_in[15];
    const float* proj_var   = (const float*)d_in[16];
    float* out = (float*)d_out;

    _Float16* h0 = (_Float16*)d_ws;         // X0 (b,s,t)-major
    _Float16* h1 = h0 + NELEM;              // X1
    _Float16* Wq0 = h1 + NELEM;             // 768x384
    _Float16* Wq1 = Wq0 + 768 * C_DIM;
    _Float16* Wp0 = Wq1 + 768 * C_DIM;      // 384x384
    _Float16* Wp1 = Wp0 + C_DIM * C_DIM;
    float2*   invshQ = (float2*)(Wp1 + C_DIM * C_DIM);   // 768 (q|k)
    float2*   invshP = invshQ + 768;                     // 384 (proj)
    unsigned char* spkQ  = (unsigned char*)(invshP + 384);  // NBS*384
    unsigned char* spkK  = spkQ + (size_t)NBS * C_DIM;
    unsigned char* attnB = spkK + (size_t)NBS * C_DIM;      // NBS*8

    split_w<<<1728, 256, 0, stream>>>(q_w, k_w, proj_w,
                                      q_gamma, q_beta, q_mean, q_var,
                                      k_gamma, k_beta, k_mean, k_var,
                                      Wq0, Wq1, Wp0, Wp1, invshQ);
    {
        struct L { static __global__ void k(const float* g, const float* b,
                                            const float* m, const float* v,
                                            float2* is) {
            const int i = blockIdx.x * 64 + threadIdx.x;
            if (i < 384) {
                const float inv = g[i] / sqrtf(v[i] + 1e-5f);
                is[i] = make_float2(inv, b[i] - m[i] * inv);
            }
        } };
        L::k<<<6, 64, 0, stream>>>(proj_gamma, proj_beta, proj_mean, proj_var,
                                   invshP);
    }
    split_x<<<dim3(128, 12), 256, 0, stream>>>(x, h0, h1);

    qk_mfma<<<dim3(196, 6), 256, 0, stream>>>(Wq0, Wq1, h0, h1, invshQ,
                                              spkQ, spkK);
    attn_compute<<<196, 256, 0, stream>>>(spkQ, attnB);
    proj_mfma<<<dim3(196, 3), 256, 0, stream>>>(Wp0, Wp1, spkK, attnB,
                                                proj_b, invshP, out);
}

// Round 9
// 204.523 us; speedup vs baseline: 1.9937x; 1.0690x over previous
//
#include <hip/hip_runtime.h>

#define C_DIM 384
#define S_DIM 196
#define CS_   (C_DIM * S_DIM)      // 75264
#define BCS   (32 * CS_)           // 2408448 elements per t-slab (B*C*S)
#define NELEM (128 * CS_)          // 9633792 total per tensor
#define NBS   6272                 // 32 * 196 (b,s) pairs

typedef _Float16 half8  __attribute__((ext_vector_type(8)));
typedef float    floatx4 __attribute__((ext_vector_type(4)));

// async 16B/lane global->LDS copy; LDS base wave-uniform, HW adds lane*16.
__device__ __forceinline__ void gl_lds16(const _Float16* g, _Float16* l) {
    __builtin_amdgcn_global_load_lds(
        (const __attribute__((address_space(1))) unsigned int*)g,
        (__attribute__((address_space(3))) unsigned int*)l, 16, 0, 0);
}

// ---------------------------------------------------------------------------
// Split weights into fp16 hi/lo(x4096) planes; precompute BN inv/sh for
// qk (768 rows) and proj (384 rows).
// ---------------------------------------------------------------------------
__global__ __launch_bounds__(256)
void split_w(const float* __restrict__ qw, const float* __restrict__ kw,
             const float* __restrict__ pw,
             const float* qg, const float* qb, const float* qm, const float* qv,
             const float* kg, const float* kb, const float* km, const float* kv,
             const float* pg, const float* pb, const float* pm, const float* pv,
             _Float16* __restrict__ Wq0, _Float16* __restrict__ Wq1,
             _Float16* __restrict__ Wp0, _Float16* __restrict__ Wp1,
             float2* __restrict__ invshQ, float2* __restrict__ invshP)
{
    const int i = blockIdx.x * 256 + threadIdx.x;
    const int NQ = 768 * C_DIM;
    if (i < NQ) {
        const int o = i / C_DIM, c = i - o * C_DIM;
        const float v = (o < 384) ? qw[o * C_DIM + c] : kw[(o - 384) * C_DIM + c];
        const _Float16 h0 = (_Float16)v;
        Wq0[i] = h0;
        Wq1[i] = (_Float16)((v - (float)h0) * 4096.0f);
    } else if (i < NQ + C_DIM * C_DIM) {
        const int j = i - NQ;
        const float v = pw[j];
        const _Float16 h0 = (_Float16)v;
        Wp0[j] = h0;
        Wp1[j] = (_Float16)((v - (float)h0) * 4096.0f);
    }
    if (i < 768) {
        float g, b, m, vv;
        if (i < 384) { g = qg[i]; b = qb[i]; m = qm[i]; vv = qv[i]; }
        else         { g = kg[i-384]; b = kb[i-384]; m = km[i-384]; vv = kv[i-384]; }
        const float inv = g / sqrtf(vv + 1e-5f);
        invshQ[i] = make_float2(inv, b - m * inv);
    } else if (i < 1152) {
        const int j = i - 768;
        const float inv = pg[j] / sqrtf(pv[j] + 1e-5f);
        invshP[j] = make_float2(inv, pb[j] - pm[j] * inv);
    }
}

// ---------------------------------------------------------------------------
// Split + transpose X: [t][b][c][s] fp32 -> X0/X1 [m'=(b*196+s)*4+t][c] fp16.
// ---------------------------------------------------------------------------
__global__ __launch_bounds__(256)
void split_x(const float* __restrict__ X,
             _Float16* __restrict__ X0, _Float16* __restrict__ X1)
{
    __shared__ float tile[32][201];
    const int tb = blockIdx.x;          // t*32 + b
    const int tt = tb >> 5, b = tb & 31;
    const int c0 = blockIdx.y * 32;
    const int t  = threadIdx.x;
    for (int idx = t; idx < 32 * S_DIM; idx += 256) {
        const int cc = idx / S_DIM, s = idx - cc * S_DIM;
        tile[cc][s] = X[(size_t)tb * CS_ + (c0 + cc) * S_DIM + s];
    }
    __syncthreads();
    for (int idx = t; idx < 32 * S_DIM; idx += 256) {
        const int s = idx >> 5, cc = idx & 31;
        const float v = tile[cc][s];
        const _Float16 h0 = (_Float16)v;
        const size_t off = ((size_t)(b * S_DIM + s) * 4 + tt) * C_DIM + c0 + cc;
        X0[off] = h0;
        X1[off] = (_Float16)((v - (float)h0) * 4096.0f);
    }
}

// ---------------------------------------------------------------------------
// Fused-split qk GEMM + BN + IN-LANE LIF -> spike bytes [bs][c].
// X = A-operand (D rows = m' = bs*4+t), W = B-operand (D cols = o).
// acc += X0*W1 + X1*W0 + (4096*X0)*W0; x = acc*2^-12*inv+sh.
// ---------------------------------------------------------------------------
__global__ __launch_bounds__(256, 3)
void qk_mfma(const _Float16* __restrict__ A0, const _Float16* __restrict__ A1,
             const _Float16* __restrict__ B0, const _Float16* __restrict__ B1,
             const float2* __restrict__ invsh,
             unsigned char* __restrict__ spkQ, unsigned char* __restrict__ spkK)
{
    __shared__ __align__(16) _Float16 As0[128 * 32];   // W0 tile (o rows)
    __shared__ __align__(16) _Float16 As1[128 * 32];   // W1 tile
    __shared__ __align__(16) _Float16 Bs0[128 * 32];   // X0 tile (m' rows)
    __shared__ __align__(16) _Float16 Bs1[128 * 32];   // X1 tile

    const int t    = threadIdx.x;
    const int wave = t >> 6, lane = t & 63;
    const int m0 = blockIdx.x * 128;
    const int o0 = blockIdx.y * 128;

    const int wR   = wave * 32;
    const int sRow = lane >> 2;
    const int sCol = (((lane & 3) ^ ((sRow >> 1) & 3))) << 3;

    const int lo = lane & 15, quad = lane >> 4;
    const int oq = (wave >> 1) * 64, mq = (wave & 1) * 64;
    const int rdC = (quad ^ ((lo >> 1) & 3)) << 3;

    floatx4 acc[4][4];   // [i = m-frag][j = o-frag]
    #pragma unroll
    for (int i = 0; i < 4; ++i)
        #pragma unroll
        for (int j = 0; j < 4; ++j) acc[i][j] = (floatx4)0.0f;

    for (int kt = 0; kt < 12; ++kt) {
        __syncthreads();
        const int kb = kt * 32;
        #pragma unroll
        for (int u = 0; u < 2; ++u) {
            const int R = wR + u * 16;
            const size_t ga = (size_t)(o0 + R + sRow) * C_DIM + kb + sCol;
            const size_t gb = (size_t)(m0 + R + sRow) * C_DIM + kb + sCol;
            gl_lds16(A0 + ga, &As0[R * 32]);
            gl_lds16(A1 + ga, &As1[R * 32]);
            gl_lds16(B0 + gb, &Bs0[R * 32]);
            gl_lds16(B1 + gb, &Bs1[R * 32]);
        }
        __syncthreads();

        half8 w0F[4], w1F[4], x0F[4], x1F[4];
        #pragma unroll
        for (int j = 0; j < 4; ++j) {
            const int ra = (oq + j * 16 + lo) * 32 + rdC;
            w0F[j] = *(const half8*)&As0[ra];
            w1F[j] = *(const half8*)&As1[ra];
        }
        #pragma unroll
        for (int i = 0; i < 4; ++i) {
            const int rb = (mq + i * 16 + lo) * 32 + rdC;
            x0F[i] = *(const half8*)&Bs0[rb];
            x1F[i] = *(const half8*)&Bs1[rb];
        }
        #pragma unroll
        for (int i = 0; i < 4; ++i) {
            const half8 xS = x0F[i] * (_Float16)4096.0f;   // exact pow2 scale
            #pragma unroll
            for (int j = 0; j < 4; ++j) {
                acc[i][j] = __builtin_amdgcn_mfma_f32_16x16x32_f16(
                    x0F[i], w1F[j], acc[i][j], 0, 0, 0);
                acc[i][j] = __builtin_amdgcn_mfma_f32_16x16x32_f16(
                    x1F[i], w0F[j], acc[i][j], 0, 0, 0);
                acc[i][j] = __builtin_amdgcn_mfma_f32_16x16x32_f16(
                    xS,     w0F[j], acc[i][j], 0, 0, 0);
            }
        }
    }

    // epilogue: D rows = m' (quad picks bs, reg picks t), cols = o.
    #pragma unroll
    for (int j = 0; j < 4; ++j) {
        const int o = o0 + oq + j * 16 + lo;
        const float2 is = invsh[o];
        const float inv = is.x * (1.0f / 4096.0f);
        const float sh  = is.y;
        unsigned char* base = (o < 384) ? spkQ : spkK;
        const int orow = (o < 384) ? o : o - 384;
        #pragma unroll
        for (int i = 0; i < 4; ++i) {
            const int bs = ((m0 + mq + i * 16) >> 2) + quad;
            float v = 0.0f; int bits = 0;
            #pragma unroll
            for (int r = 0; r < 4; ++r) {
                const float xv = acc[i][j][r] * inv + sh;
                const float h = v + (xv - v) * 0.5f;
                const int sp = (h >= 1.0f);
                v = sp ? 0.0f : h;
                bits |= sp << r;
            }
            base[(size_t)bs * C_DIM + orow] = (unsigned char)bits;
        }
    }
}

// ---------------------------------------------------------------------------
// attn LIF per (bs, head): popcount q-spike bits over 48 contiguous bytes.
// ---------------------------------------------------------------------------
__global__ __launch_bounds__(256)
void attn_compute(const unsigned char* __restrict__ spkQ,
                  unsigned char* __restrict__ attnB)
{
    const int idx = blockIdx.x * 256 + threadIdx.x;
    if (idx >= NBS * 8) return;
    const int bs = idx >> 3, head = idx & 7;
    const unsigned long long* p =
        (const unsigned long long*)(spkQ + (size_t)bs * C_DIM + head * 48);
    int qs[4] = {0, 0, 0, 0};
    #pragma unroll
    for (int u = 0; u < 6; ++u) {
        const unsigned long long v = p[u];
        qs[0] += __popcll(v & 0x0101010101010101ull);
        qs[1] += __popcll(v & 0x0202020202020202ull);
        qs[2] += __popcll(v & 0x0404040404040404ull);
        qs[3] += __popcll(v & 0x0808080808080808ull);
    }
    float va = 0.0f;
    int bits = 0;
    #pragma unroll
    for (int t = 0; t < 4; ++t) {
        const float h = va + ((float)qs[t] - va) * 0.5f;
        const int a = (h >= 0.5f);
        va = a ? 0.0f : h;
        bits |= a << t;
    }
    attnB[idx] = (unsigned char)bits;
}

// ---------------------------------------------------------------------------
// Fused-split proj GEMM; Y (binary, from spike/attn bits) = A-operand,
// W planes = B-operand. acc += Y*W1 + Y*(4096*W0); sum = acc*2^-12.
// Epilogue: in-lane LIF -> spike bits, then per-t LDS transpose and
// coalesced float4 stores (s-contiguous, aligned).
// ---------------------------------------------------------------------------
__global__ __launch_bounds__(256, 3)
void proj_mfma(const _Float16* __restrict__ A0, const _Float16* __restrict__ A1,
               const unsigned char* __restrict__ spkK,
               const unsigned char* __restrict__ attnB,
               const float* __restrict__ bias, const float2* __restrict__ invsh,
               float* __restrict__ out)
{
    __shared__ __align__(16) _Float16 smem[3 * 128 * 32];   // 24 KB
    _Float16* As0 = smem;                 // W0 (o rows)
    _Float16* As1 = smem + 4096;          // W1
    _Float16* Bs0 = smem + 8192;          // Y  (m' rows)

    const int t    = threadIdx.x;
    const int wave = t >> 6, lane = t & 63;
    const int m0 = blockIdx.x * 128;
    const int o0 = blockIdx.y * 128;

    const int wR   = wave * 32;
    const int sRow = lane >> 2;
    const int sCol = (((lane & 3) ^ ((sRow >> 1) & 3))) << 3;   // A glds swizzle
    const int gC8  = (lane & 3) << 3;                            // B global chunk
    const int pC8  = sCol;                                       // B LDS swizzle

    const int lo = lane & 15, quad = lane >> 4;
    const int oq = (wave >> 1) * 64, mq = (wave & 1) * 64;
    const int rdC = (quad ^ ((lo >> 1) & 3)) << 3;

    const int bsL[2] = { (m0 + wR +  0 + sRow) >> 2, (m0 + wR + 16 + sRow) >> 2 };
    const int ttL    = (m0 + wR + sRow) & 3;

    floatx4 acc[4][4];   // [i = m-frag][j = o-frag]
    #pragma unroll
    for (int i = 0; i < 4; ++i)
        #pragma unroll
        for (int j = 0; j < 4; ++j) acc[i][j] = (floatx4)0.0f;

    unsigned long long rk[2];
    int rab[2];
    {
        const int head0 = gC8 / 48;
        #pragma unroll
        for (int u = 0; u < 2; ++u) {
            rk[u]  = *(const unsigned long long*)(spkK + (size_t)bsL[u] * C_DIM + gC8);
            rab[u] = (attnB[bsL[u] * 8 + head0] >> ttL) & 1;
        }
    }

    for (int kt = 0; kt < 12; ++kt) {
        __syncthreads();
        const int kb = kt * 32;
        #pragma unroll
        for (int u = 0; u < 2; ++u) {
            const int R = wR + u * 16;
            half8 bv;
            #pragma unroll
            for (int e = 0; e < 8; ++e)
                bv[e] = (_Float16)(float)((int)(rk[u] >> (8 * e + ttL)) & rab[u] & 1);
            *(half8*)&Bs0[(R + sRow) * 32 + pC8] = bv;
            const size_t ga = (size_t)(o0 + R + sRow) * C_DIM + kb + sCol;
            gl_lds16(A0 + ga, &As0[R * 32]);
            gl_lds16(A1 + ga, &As1[R * 32]);
        }
        if (kt < 11) {
            const int kb2  = (kt + 1) * 32;
            const int head = (kb2 + gC8) / 48;
            #pragma unroll
            for (int u = 0; u < 2; ++u) {
                rk[u]  = *(const unsigned long long*)(spkK + (size_t)bsL[u] * C_DIM + kb2 + gC8);
                rab[u] = (attnB[bsL[u] * 8 + head] >> ttL) & 1;
            }
        }
        __syncthreads();

        half8 w0F[4], w1F[4], yF[4];
        #pragma unroll
        for (int j = 0; j < 4; ++j) {
            const int ra = (oq + j * 16 + lo) * 32 + rdC;
            w0F[j] = *(const half8*)&As0[ra];
            w1F[j] = *(const half8*)&As1[ra];
        }
        #pragma unroll
        for (int i = 0; i < 4; ++i)
            yF[i] = *(const half8*)&Bs0[(mq + i * 16 + lo) * 32 + rdC];

        #pragma unroll
        for (int j = 0; j < 4; ++j) {
            const half8 wS = w0F[j] * (_Float16)4096.0f;
            #pragma unroll
            for (int i = 0; i < 4; ++i) {
                acc[i][j] = __builtin_amdgcn_mfma_f32_16x16x32_f16(
                    yF[i], w1F[j], acc[i][j], 0, 0, 0);
                acc[i][j] = __builtin_amdgcn_mfma_f32_16x16x32_f16(
                    yF[i], wS,     acc[i][j], 0, 0, 0);
            }
        }
    }

    // in-lane LIF -> 4 spike bits per (i,j)
    int bits[4][4];
    #pragma unroll
    for (int j = 0; j < 4; ++j) {
        const int o = o0 + oq + j * 16 + lo;
        const float2 is = invsh[o];
        const float bv = bias[o];
        #pragma unroll
        for (int i = 0; i < 4; ++i) {
            float v = 0.0f; int bt = 0;
            #pragma unroll
            for (int r = 0; r < 4; ++r) {
                const float p = acc[i][j][r] * (1.0f / 4096.0f);
                const float z = (p + bv) * is.x + is.y;
                const float h = v + (z - v) * 0.5f;
                const int sp = (h >= 1.0f);
                v = sp ? 0.0f : h;
                bt |= sp << r;
            }
            bits[i][j] = bt;
        }
    }

    // per-t: LDS transpose (128 o x 32 bs, pad 33) + coalesced float4 stores
    float* tile = (float*)smem;            // 128*33*4 B = 16.9 KB
    const int bs0g = m0 >> 2;
    for (int r = 0; r < 4; ++r) {
        __syncthreads();
        #pragma unroll
        for (int j = 0; j < 4; ++j)
            #pragma unroll
            for (int i = 0; i < 4; ++i)
                tile[(oq + j * 16 + lo) * 33 + (mq >> 2) + i * 4 + quad] =
                    ((bits[i][j] >> r) & 1) ? 1.0f : 0.0f;
        __syncthreads();
        #pragma unroll
        for (int it = 0; it < 4; ++it) {
            const int idx = it * 256 + t;        // 0..1023
            const int o   = idx >> 3;
            const int ch  = idx & 7;
            const int bsg = bs0g + ch * 4;       // 4-chunk never straddles b
            const int b   = bsg / S_DIM;
            const int s   = bsg - b * S_DIM;
            float4 vv;
            vv.x = tile[o * 33 + ch * 4 + 0];
            vv.y = tile[o * 33 + ch * 4 + 1];
            vv.z = tile[o * 33 + ch * 4 + 2];
            vv.w = tile[o * 33 + ch * 4 + 3];
            *(float4*)(out + (size_t)r * BCS + (size_t)b * CS_
                           + (size_t)(o0 + o) * S_DIM + s) = vv;
        }
    }
}

// ---------------------------------------------------------------------------
extern "C" void kernel_launch(void* const* d_in, const int* in_sizes, int n_in,
                              void* d_out, int out_size, void* d_ws, size_t ws_size,
                              hipStream_t stream)
{
    const float* x          = (const float*)d_in[0];
    const float* q_w        = (const float*)d_in[1];
    const float* q_gamma    = (const float*)d_in[2];
    const float* q_beta     = (const float*)d_in[3];
    const float* q_mean     = (const float*)d_in[4];
    const float* q_var      = (const float*)d_in[5];
    const float* k_w        = (const float*)d_in[6];
    const float* k_gamma    = (const float*)d_in[7];
    const float* k_beta     = (const float*)d_in[8];
    const float* k_mean     = (const float*)d_in[9];
    const float* k_var      = (const float*)d_in[10];
    const float* proj_w     = (const float*)d_in[11];
    const float* proj_b     = (const float*)d_in[12];
    const float* proj_gamma = (const float*)d_in[13];
    const float* proj_beta  = (const float*)d_in[14];
    const float* proj_mean  = (const float*)d_in[15];
    const float* proj_var   = (const float*)d_in[16];
    float* out = (float*)d_out;

    _Float16* h0 = (_Float16*)d_ws;         // X0 (b,s,t)-major
    _Float16* h1 = h0 + NELEM;              // X1
    _Float16* Wq0 = h1 + NELEM;             // 768x384
    _Float16* Wq1 = Wq0 + 768 * C_DIM;
    _Float16* Wp0 = Wq1 + 768 * C_DIM;      // 384x384
    _Float16* Wp1 = Wp0 + C_DIM * C_DIM;
    float2*   invshQ = (float2*)(Wp1 + C_DIM * C_DIM);   // 768 (q|k)
    float2*   invshP = invshQ + 768;                     // 384 (proj)
    unsigned char* spkQ  = (unsigned char*)(invshP + 384);  // NBS*384
    unsigned char* spkK  = spkQ + (size_t)NBS * C_DIM;
    unsigned char* attnB = spkK + (size_t)NBS * C_DIM;      // NBS*8

    split_w<<<1728, 256, 0, stream>>>(q_w, k_w, proj_w,
                                      q_gamma, q_beta, q_mean, q_var,
                                      k_gamma, k_beta, k_mean, k_var,
                                      proj_gamma, proj_beta, proj_mean, proj_var,
                                      Wq0, Wq1, Wp0, Wp1, invshQ, invshP);
    split_x<<<dim3(128, 12), 256, 0, stream>>>(x, h0, h1);

    qk_mfma<<<dim3(196, 6), 256, 0, stream>>>(Wq0, Wq1, h0, h1, invshQ,
                                              spkQ, spkK);
    attn_compute<<<196, 256, 0, stream>>>(spkQ, attnB);
    proj_mfma<<<dim3(196, 3), 256, 0, stream>>>(Wp0, Wp1, spkK, attnB,
                                                proj_b, invshP, out);
}